// Round 1
// baseline (13337.909 us; speedup 1.0000x reference)
//
#include <hip/hip_runtime.h>
#include <hip/hip_bf16.h>

// LocalResnetPointnet: B=2, T=65536, D=3, H=128, 5 ResnetBlockFC blocks,
// scatter-mean into (B,128,128,128).
//
// ws layout (needs ~67.3 MB):
//   hA: ushort[128*131072] (bf16, [ch][point])   33.55 MB
//   hB: same                                     33.55 MB
//   pools: uint[5][2][128]
//   b0e/bse: float[4][2][128] each
//   Sp: float[3][128], bsp: float[128]
//   cnt: float[2][16384]

#define G_ALL 131072   // B*T
#define HD 128
#define NBINS 16384

__device__ __forceinline__ float bf16_to_f32(unsigned short u) {
  union { unsigned int u; float f; } v; v.u = ((unsigned int)u) << 16; return v.f;
}
__device__ __forceinline__ unsigned short f32_to_bf16(float f) {
  union { float f; unsigned int u; } v; v.f = f;
  unsigned int u = v.u;
  u += 0x7fffu + ((u >> 16) & 1u);   // round-to-nearest-even (no NaNs here)
  return (unsigned short)(u >> 16);
}
// order-preserving float -> uint key for atomicMax (works for negatives)
__device__ __forceinline__ unsigned int f32_key(float f) {
  union { float f; unsigned int u; } v; v.f = f;
  return (v.u & 0x80000000u) ? ~v.u : (v.u | 0x80000000u);
}
__device__ __forceinline__ float key_f32(unsigned int k) {
  union { unsigned int u; float f; } v;
  v.u = (k & 0x80000000u) ? (k & 0x7fffffffu) : ~k;
  return v.f;
}

// ---------------- prep: Sp = Wp@ws0 (3x128), bsp = bp@ws0, zero pools+cnt ---
__global__ void prep_kernel(const float* __restrict__ fcw,
                            const float* __restrict__ fcb,
                            const float* __restrict__ ws0,
                            float* __restrict__ Sp, float* __restrict__ bsp,
                            unsigned int* __restrict__ pools,
                            float* __restrict__ cnt) {
  int j = threadIdx.x;  // 128 threads
  for (int d = 0; d < 3; d++) {
    float s = 0.f;
    for (int ch = 0; ch < 256; ch++)
      s = fmaf(fcw[d * 256 + ch], ws0[ch * HD + j], s);
    Sp[d * HD + j] = s;
  }
  float s = 0.f;
  for (int ch = 0; ch < 256; ch++)
    s = fmaf(fcb[ch], ws0[ch * HD + j], s);
  bsp[j] = s;
  for (int k = j; k < 5 * 2 * 128; k += 128) pools[k] = 0u;
  for (int k = j; k < 2 * NBINS; k += 128) cnt[k] = 0.f;
}

// ---------------- fold: per-batch effective biases from pooled vector -------
__global__ void fold_kernel(const unsigned int* __restrict__ poolPrev,  // [2][128]
                            const float* __restrict__ b0s,
                            const float* __restrict__ b1s,
                            const float* __restrict__ w0hi,  // rows 128..255 of w0[s]
                            const float* __restrict__ wshi,  // rows 128..255 of ws[s]
                            float* __restrict__ b0e, float* __restrict__ bse) {
  int tid = threadIdx.x;  // 256
  int b = tid >> 7, j = tid & 127;
  float a0 = b0s[j], a1 = b1s[j];
  for (int ch = 0; ch < 128; ch++) {
    float pv = key_f32(poolPrev[b * 128 + ch]);
    a0 = fmaf(fmaxf(pv, 0.f), w0hi[ch * HD + j], a0);
    a1 = fmaf(pv, wshi[ch * HD + j], a1);
  }
  b0e[b * 128 + j] = a0;
  bse[b * 128 + j] = a1;
}

// ---------------- stage 0: fc_pos + block0 ---------------------------------
__global__ __launch_bounds__(256, 2) void stage0_kernel(
    const float* __restrict__ p, const float* __restrict__ fcw,
    const float* __restrict__ fcb, const float* __restrict__ w0,
    const float* __restrict__ b0, const float* __restrict__ w1,
    const float* __restrict__ b1, const float* __restrict__ Sp,
    const float* __restrict__ bsp, unsigned short* __restrict__ hout,
    unsigned int* __restrict__ pool) {
  __shared__ unsigned short m[HD * 256];  // 64 KB
  int tid = threadIdx.x;
  int g = blockIdx.x * 256 + tid;
  int b = g >> 16;
  float p0 = p[3 * g], p1 = p[3 * g + 1], p2 = p[3 * g + 2];

  float acc[HD];
#pragma unroll
  for (int j = 0; j < HD; j++) acc[j] = b0[j];
  // net = relu(x0) @ w0[0]  (K = 256, x0 computed on the fly)
  for (int ch = 0; ch < 256; ch++) {
    float x0 = fcb[ch];
    x0 = fmaf(p0, fcw[ch], x0);
    x0 = fmaf(p1, fcw[256 + ch], x0);
    x0 = fmaf(p2, fcw[512 + ch], x0);
    float r = fmaxf(x0, 0.f);
    const float* wr = w0 + ch * HD;
#pragma unroll
    for (int j = 0; j < HD; j++) acc[j] = fmaf(r, wr[j], acc[j]);
  }
#pragma unroll
  for (int j = 0; j < HD; j++)
    m[j * 256 + tid] = f32_to_bf16(fmaxf(acc[j], 0.f));
  __syncthreads();
  // dx = m @ w1[0] + b1[0]; shortcut = p@Sp + bsp (folded fc_pos)
#pragma unroll
  for (int j = 0; j < HD; j++) {
    float a = bsp[j] + b1[j];
    a = fmaf(p0, Sp[j], a);
    a = fmaf(p1, Sp[HD + j], a);
    a = fmaf(p2, Sp[2 * HD + j], a);
    acc[j] = a;
  }
  for (int ch = 0; ch < 128; ch++) {
    float mv = bf16_to_f32(m[ch * 256 + tid]);
    const float* wr = w1 + ch * HD;
#pragma unroll
    for (int j = 0; j < HD; j++) acc[j] = fmaf(mv, wr[j], acc[j]);
  }
#pragma unroll
  for (int j = 0; j < HD; j++) hout[j * G_ALL + g] = f32_to_bf16(acc[j]);
  // per-wave max then atomicMax into pool[b][j]
  for (int j = 0; j < HD; j++) {
    float v = acc[j];
#pragma unroll
    for (int off = 32; off > 0; off >>= 1) v = fmaxf(v, __shfl_xor(v, off, 64));
    if ((tid & 63) == 0) atomicMax(&pool[b * 128 + j], f32_key(v));
  }
}

// ---------------- stages 1..4 ----------------------------------------------
__global__ __launch_bounds__(256, 2) void stageN_kernel(
    const unsigned short* __restrict__ hin, unsigned short* __restrict__ hout,
    const float* __restrict__ w0s,   // w0[s] rows 0..127
    const float* __restrict__ w1s,
    const float* __restrict__ wss,   // ws[s] rows 0..127
    const float* __restrict__ b0e,   // [2][128] folded
    const float* __restrict__ bse,   // [2][128] folded (includes b1)
    unsigned int* __restrict__ pool, int doPool) {
  __shared__ unsigned short m[HD * 256];  // 64 KB
  int tid = threadIdx.x;
  int g = blockIdx.x * 256 + tid;
  int b = g >> 16;

  float acc[HD];
#pragma unroll
  for (int j = 0; j < HD; j++) acc[j] = b0e[b * 128 + j];
  // net = relu(h) @ w0[:128] + b0eff
  for (int ch = 0; ch < 128; ch++) {
    float hv = bf16_to_f32(hin[ch * G_ALL + g]);
    float r = fmaxf(hv, 0.f);
    const float* wr = w0s + ch * HD;
#pragma unroll
    for (int j = 0; j < HD; j++) acc[j] = fmaf(r, wr[j], acc[j]);
  }
#pragma unroll
  for (int j = 0; j < HD; j++)
    m[j * 256 + tid] = f32_to_bf16(fmaxf(acc[j], 0.f));
  __syncthreads();
  // h_next = m@w1 + h@ws[:128] + bseff
#pragma unroll
  for (int j = 0; j < HD; j++) acc[j] = bse[b * 128 + j];
  for (int ch = 0; ch < 128; ch++) {
    float mv = bf16_to_f32(m[ch * 256 + tid]);
    float hv = bf16_to_f32(hin[ch * G_ALL + g]);
    const float* w1r = w1s + ch * HD;
    const float* wsr = wss + ch * HD;
#pragma unroll
    for (int j = 0; j < HD; j++)
      acc[j] = fmaf(mv, w1r[j], fmaf(hv, wsr[j], acc[j]));
  }
#pragma unroll
  for (int j = 0; j < HD; j++) hout[j * G_ALL + g] = f32_to_bf16(acc[j]);
  if (doPool) {
    for (int j = 0; j < HD; j++) {
      float v = acc[j];
#pragma unroll
      for (int off = 32; off > 0; off >>= 1) v = fmaxf(v, __shfl_xor(v, off, 64));
      if ((tid & 63) == 0) atomicMax(&pool[b * 128 + j], f32_key(v));
    }
  }
}

// ---------------- scatter-add into transposed plane layout -----------------
__global__ __launch_bounds__(256) void scatter_kernel(
    const float* __restrict__ p, const unsigned short* __restrict__ c,
    float* __restrict__ out, float* __restrict__ cnt) {
  int g = blockIdx.x * 256 + threadIdx.x;
  int b = g >> 16;
  float p0 = p[3 * g], p2 = p[3 * g + 2];
  // match reference fp32 op order exactly: x/(1.101) + 0.5, clip, *128, trunc
  float x = p0 / 1.101f + 0.5f;
  x = fminf(fmaxf(x, 0.0f), 1.0f - 1e-6f);
  int xi = (int)(x * 128.0f);
  float z = p2 / 1.101f + 0.5f;
  z = fminf(fmaxf(z, 0.0f), 1.0f - 1e-6f);
  int zi = (int)(z * 128.0f);
  int idx = xi + 128 * zi;
  atomicAdd(cnt + b * NBINS + idx, 1.0f);
  float* ob = out + (size_t)b * HD * NBINS + idx;
  for (int ch = 0; ch < HD; ch++)
    atomicAdd(ob + (size_t)ch * NBINS, bf16_to_f32(c[ch * G_ALL + g]));
}

// ---------------- normalize: out /= max(cnt,1) -----------------------------
__global__ void norm_kernel(float* __restrict__ out,
                            const float* __restrict__ cnt) {
  int e = blockIdx.x * 256 + threadIdx.x;  // 2*128*16384 = 2^22 total
  int b = e >> 21;
  int idx = e & (NBINS - 1);
  out[e] = out[e] / fmaxf(cnt[b * NBINS + idx], 1.0f);
}

extern "C" void kernel_launch(void* const* d_in, const int* in_sizes, int n_in,
                              void* d_out, int out_size, void* d_ws,
                              size_t ws_size, hipStream_t stream) {
  const float* p   = (const float*)d_in[0];
  const float* fcw = (const float*)d_in[1];
  const float* fcb = (const float*)d_in[2];
  const float* w0  = (const float*)d_in[3];
  const float* b0  = (const float*)d_in[4];
  const float* w1  = (const float*)d_in[5];
  const float* b1  = (const float*)d_in[6];
  const float* wsc = (const float*)d_in[7];
  float* out = (float*)d_out;

  char* wsp = (char*)d_ws;
  unsigned short* hA = (unsigned short*)wsp;
  unsigned short* hB = hA + (size_t)HD * G_ALL;
  unsigned int* pools = (unsigned int*)(hB + (size_t)HD * G_ALL);  // [5][2][128]
  float* b0e = (float*)(pools + 5 * 2 * 128);  // [4][2][128]
  float* bse = b0e + 4 * 2 * 128;
  float* Sp  = bse + 4 * 2 * 128;
  float* bsp = Sp + 3 * HD;
  float* cnt = bsp + HD;

  hipMemsetAsync(d_out, 0, (size_t)2 * HD * NBINS * sizeof(float), stream);
  prep_kernel<<<1, 128, 0, stream>>>(fcw, fcb, wsc, Sp, bsp, pools, cnt);
  stage0_kernel<<<512, 256, 0, stream>>>(p, fcw, fcb, w0, b0, w1, b1, Sp, bsp,
                                         hA, pools);
  const unsigned short* hin = hA;
  unsigned short* hout = hB;
  for (int s = 1; s < 5; s++) {
    fold_kernel<<<1, 256, 0, stream>>>(
        pools + (s - 1) * 256, b0 + s * HD, b1 + s * HD,
        w0 + (size_t)(s * 256 + 128) * HD, wsc + (size_t)(s * 256 + 128) * HD,
        b0e + (s - 1) * 256, bse + (s - 1) * 256);
    stageN_kernel<<<512, 256, 0, stream>>>(
        hin, hout, w0 + (size_t)s * 256 * HD, w1 + (size_t)s * HD * HD,
        wsc + (size_t)s * 256 * HD, b0e + (s - 1) * 256, bse + (s - 1) * 256,
        pools + s * 256, (s < 4) ? 1 : 0);
    const unsigned short* t = hin;
    hin = hout;
    hout = (unsigned short*)t;
  }
  scatter_kernel<<<512, 256, 0, stream>>>(p, hin, out, cnt);
  norm_kernel<<<16384, 256, 0, stream>>>(out, cnt);
}

// Round 2
// 2115.487 us; speedup vs baseline: 6.3049x; 6.3049x over previous
//
#include <hip/hip_runtime.h>
#include <hip/hip_bf16.h>

// LocalResnetPointnet MFMA version.
// Activations: bf16, layout [point][ch] (row-major, 128 ch = 256 B rows).
// Weights: pre-transposed Bt[n][k] bf16, hi/lo split for fp32-accurate weights.

#define G_ALL 131072   // B*T
#define TB    65536
#define HD    128
#define NBINS 16384

typedef __attribute__((ext_vector_type(8))) short short8;
typedef __attribute__((ext_vector_type(4))) float f32x4;

#define MFMA16(a, b, c) __builtin_amdgcn_mfma_f32_16x16x32_bf16(a, b, c, 0, 0, 0)

__device__ __forceinline__ float bf16_to_f32(unsigned short u) {
  union { unsigned int u; float f; } v; v.u = ((unsigned int)u) << 16; return v.f;
}
__device__ __forceinline__ unsigned short f32_to_bf16(float f) {
  union { float f; unsigned int u; } v; v.f = f;
  unsigned int u = v.u;
  u += 0x7fffu + ((u >> 16) & 1u);   // RNE (no NaNs in this workload)
  return (unsigned short)(u >> 16);
}

// ---------------- prep: Sp = fcw@ws0 (3x128), bsp = fcb@ws0, zero cnt ------
__global__ void prep_kernel(const float* __restrict__ fcw,
                            const float* __restrict__ fcb,
                            const float* __restrict__ ws0,
                            float* __restrict__ Sp, float* __restrict__ bsp,
                            float* __restrict__ cnt) {
  int j = threadIdx.x;  // 128 threads
  for (int d = 0; d < 3; d++) {
    float s = 0.f;
    for (int ch = 0; ch < 256; ch++)
      s = fmaf(fcw[d * 256 + ch], ws0[ch * HD + j], s);
    Sp[d * HD + j] = s;
  }
  float s = 0.f;
  for (int ch = 0; ch < 256; ch++)
    s = fmaf(fcb[ch], ws0[ch * HD + j], s);
  bsp[j] = s;
  for (int k = j; k < 2 * NBINS; k += 128) cnt[k] = 0.f;
}

// ---------------- weight transform: transpose + bf16 hi/lo split -----------
// B0t: [128][256] from w0[0]; W0t[s-1]: [128][128] rows0..127 of w0[s];
// W1t[s]: [128][128]; WSt[s-1]: [128][128] rows0..127 of ws[s].
__global__ void wprep_kernel(const float* __restrict__ w0,
                             const float* __restrict__ w1,
                             const float* __restrict__ ws,
                             unsigned short* __restrict__ B0hi, unsigned short* __restrict__ B0lo,
                             unsigned short* __restrict__ W0hi, unsigned short* __restrict__ W0lo,
                             unsigned short* __restrict__ W1hi, unsigned short* __restrict__ W1lo,
                             unsigned short* __restrict__ WShi, unsigned short* __restrict__ WSlo) {
  int gid = blockIdx.x * 256 + threadIdx.x;
  float v;
  unsigned short *hi, *lo;
  int dst;
  if (gid < 32768) {                       // B0t: n = gid>>8, k = gid&255
    int n = gid >> 8, k = gid & 255;
    v = w0[k * 128 + n];
    hi = B0hi; lo = B0lo; dst = gid;
  } else if (gid < 98304) {                // W0t stages 1..4
    int i = gid - 32768; int s = i >> 14; int n = (i >> 7) & 127; int k = i & 127;
    v = w0[(size_t)((s + 1) * 256 + k) * 128 + n];
    hi = W0hi; lo = W0lo; dst = i;
  } else if (gid < 180224) {               // W1t stages 0..4
    int i = gid - 98304; int s = i >> 14; int n = (i >> 7) & 127; int k = i & 127;
    v = w1[(size_t)(s * 128 + k) * 128 + n];
    hi = W1hi; lo = W1lo; dst = i;
  } else if (gid < 245760) {               // WSt stages 1..4
    int i = gid - 180224; int s = i >> 14; int n = (i >> 7) & 127; int k = i & 127;
    v = ws[(size_t)((s + 1) * 256 + k) * 128 + n];
    hi = WShi; lo = WSlo; dst = i;
  } else return;
  unsigned short h = f32_to_bf16(v);
  hi[dst] = h;
  lo[dst] = f32_to_bf16(v - bf16_to_f32(h));
}

// ---------------- fold: pooled max + per-batch effective biases ------------
__global__ void fold_kernel(const float* __restrict__ pmax, int nb,
                            const float* __restrict__ b0s,
                            const float* __restrict__ b1s,
                            const float* __restrict__ w0hi,  // f32, rows 128..255
                            const float* __restrict__ wshi,
                            float* __restrict__ b0e, float* __restrict__ bse) {
  __shared__ float ps[256];
  int tid = threadIdx.x;  // 256
  int b = tid >> 7, j = tid & 127;
  float v = -1e30f;
  for (int i = 0; i < nb; i++)
    v = fmaxf(v, pmax[(size_t)(b * nb + i) * 128 + j]);
  ps[tid] = v;
  __syncthreads();
  float a0 = b0s[j], a1 = b1s[j];
  for (int ch = 0; ch < 128; ch++) {
    float pv = ps[b * 128 + ch];
    a0 = fmaf(fmaxf(pv, 0.f), w0hi[ch * HD + j], a0);
    a1 = fmaf(pv, wshi[ch * HD + j], a1);
  }
  b0e[b * 128 + j] = a0;
  bse[b * 128 + j] = a1;
}

// ---------------- stage 0: fc_pos + block0 (MFMA) --------------------------
// block = 64 points, 4 waves x 16 rows. K=256 for first matmul.
__global__ __launch_bounds__(256) void stage0_kernel(
    const float* __restrict__ p, const float* __restrict__ fcw,
    const float* __restrict__ fcb,
    const unsigned short* __restrict__ B0hi, const unsigned short* __restrict__ B0lo,
    const unsigned short* __restrict__ W1hi, const unsigned short* __restrict__ W1lo,
    const float* __restrict__ b0, const float* __restrict__ b1,
    const float* __restrict__ Sp, const float* __restrict__ bsp,
    unsigned short* __restrict__ hout, float* __restrict__ pmax) {
  __shared__ float pt[64 * 4];
  __shared__ unsigned short x0t[64 * 264];   // relu(fc_pos) tile, K=256 (pad 264)
  __shared__ unsigned short m2[64 * 136];    // net relu tile (pad 136)
  const int tid = threadIdx.x;
  const int wave = tid >> 6, lane = tid & 63;
  const int q = lane >> 4, l15 = lane & 15;
  const int rowBase = blockIdx.x * 64;

  for (int i = tid; i < 192; i += 256) pt[(i / 3) * 4 + (i % 3)] = p[(size_t)rowBase * 3 + i];
  __syncthreads();
  {
    int row = tid >> 2, c0 = (tid & 3) * 64;
    float p0 = pt[row * 4], p1 = pt[row * 4 + 1], p2 = pt[row * 4 + 2];
    for (int c = c0; c < c0 + 64; c++) {
      float x = fcb[c] + p0 * fcw[c] + p1 * fcw[256 + c] + p2 * fcw[512 + c];
      x0t[row * 264 + c] = f32_to_bf16(fmaxf(x, 0.f));
    }
  }
  __syncthreads();

  // phase 1: net = relu(x0) @ W0[0] + b0[0]   (K = 256)
  short8 Ar[8];
#pragma unroll
  for (int kc = 0; kc < 8; kc++)
    Ar[kc] = *(const short8*)(&x0t[(wave * 16 + l15) * 264 + kc * 32 + q * 8]);
  f32x4 C[8];
#pragma unroll
  for (int nt = 0; nt < 8; nt++) {
    float bv = b0[nt * 16 + l15];
    C[nt] = (f32x4){bv, bv, bv, bv};
  }
  for (int kc = 0; kc < 8; kc++) {
#pragma unroll
    for (int nt = 0; nt < 8; nt++) {
      const unsigned short* bp = B0hi + (size_t)(nt * 16 + l15) * 256 + kc * 32 + q * 8;
      const unsigned short* bl = B0lo + (size_t)(nt * 16 + l15) * 256 + kc * 32 + q * 8;
      short8 bh = *(const short8*)bp;
      short8 bo = *(const short8*)bl;
      C[nt] = MFMA16(Ar[kc], bh, C[nt]);
      C[nt] = MFMA16(Ar[kc], bo, C[nt]);
    }
  }
#pragma unroll
  for (int nt = 0; nt < 8; nt++)
#pragma unroll
    for (int r = 0; r < 4; r++)
      m2[(wave * 16 + q * 4 + r) * 136 + nt * 16 + l15] =
          f32_to_bf16(fmaxf(C[nt][r], 0.f));
  __syncthreads();

  // phase 2: h = m2 @ W1[0] + (p @ Sp + bsp + b1[0])
  short8 Am[4];
#pragma unroll
  for (int kc = 0; kc < 4; kc++)
    Am[kc] = *(const short8*)(&m2[(wave * 16 + l15) * 136 + kc * 32 + q * 8]);
  float pr0[4], pr1[4], pr2[4];
#pragma unroll
  for (int r = 0; r < 4; r++) {
    int row = wave * 16 + q * 4 + r;
    pr0[r] = pt[row * 4]; pr1[r] = pt[row * 4 + 1]; pr2[r] = pt[row * 4 + 2];
  }
  f32x4 C2[8];
#pragma unroll
  for (int nt = 0; nt < 8; nt++) {
    int c = nt * 16 + l15;
    float bb = bsp[c] + b1[c];
    float s0 = Sp[c], s1 = Sp[128 + c], s2 = Sp[256 + c];
#pragma unroll
    for (int r = 0; r < 4; r++)
      C2[nt][r] = bb + pr0[r] * s0 + pr1[r] * s1 + pr2[r] * s2;
  }
  for (int kc = 0; kc < 4; kc++) {
#pragma unroll
    for (int nt = 0; nt < 8; nt++) {
      short8 bh = *(const short8*)(W1hi + (size_t)(nt * 16 + l15) * 128 + kc * 32 + q * 8);
      short8 bo = *(const short8*)(W1lo + (size_t)(nt * 16 + l15) * 128 + kc * 32 + q * 8);
      C2[nt] = MFMA16(Am[kc], bh, C2[nt]);
      C2[nt] = MFMA16(Am[kc], bo, C2[nt]);
    }
  }
  __syncthreads();  // m2 reads done everywhere before reuse as out tile
#pragma unroll
  for (int nt = 0; nt < 8; nt++)
#pragma unroll
    for (int r = 0; r < 4; r++)
      m2[(wave * 16 + q * 4 + r) * 136 + nt * 16 + l15] = f32_to_bf16(C2[nt][r]);
  __syncthreads();
  {
    int r = tid >> 2, seg = tid & 3;
#pragma unroll
    for (int i = 0; i < 4; i++) {
      short8 v = *(const short8*)(&m2[r * 136 + seg * 32 + i * 8]);
      *(short8*)(hout + (size_t)(rowBase + r) * 128 + seg * 32 + i * 8) = v;
    }
  }
  if (tid < 128) {
    float v = -1e30f;
    for (int r = 0; r < 64; r++) v = fmaxf(v, bf16_to_f32(m2[r * 136 + tid]));
    pmax[(size_t)blockIdx.x * 128 + tid] = v;
  }
}

// ---------------- stages 1..4 (MFMA) ---------------------------------------
// block = 128 points, 4 waves x 32 rows (2 strips of 16).
__global__ __launch_bounds__(256) void stageN_kernel(
    const unsigned short* __restrict__ hin, unsigned short* __restrict__ hout,
    const unsigned short* __restrict__ W0hi, const unsigned short* __restrict__ W0lo,
    const unsigned short* __restrict__ W1hi, const unsigned short* __restrict__ W1lo,
    const unsigned short* __restrict__ WShi, const unsigned short* __restrict__ WSlo,
    const float* __restrict__ b0e, const float* __restrict__ bse,
    float* __restrict__ pmax, int doPool) {
  __shared__ unsigned short m2[128 * 136];
  const int tid = threadIdx.x;
  const int wave = tid >> 6, lane = tid & 63;
  const int q = lane >> 4, l15 = lane & 15;
  const int rowBase = blockIdx.x * 128;
  const int b = blockIdx.x >> 9;  // 512 blocks per batch
  const int wrow = wave * 32;

  short8 Ah[2][4], Ar[2][4];
#pragma unroll
  for (int s = 0; s < 2; s++)
#pragma unroll
    for (int kc = 0; kc < 4; kc++) {
      int m = rowBase + wrow + s * 16 + l15;
      Ah[s][kc] = *(const short8*)(hin + (size_t)m * 128 + kc * 32 + q * 8);
    }
#pragma unroll
  for (int s = 0; s < 2; s++)
#pragma unroll
    for (int kc = 0; kc < 4; kc++)
#pragma unroll
      for (int e = 0; e < 8; e++)
        Ar[s][kc][e] = Ah[s][kc][e] < 0 ? (short)0 : Ah[s][kc][e];

  // phase 1: net = relu(H) @ W0lo + b0e
  f32x4 C1[2][8];
#pragma unroll
  for (int nt = 0; nt < 8; nt++) {
    float bv = b0e[b * 128 + nt * 16 + l15];
    C1[0][nt] = (f32x4){bv, bv, bv, bv};
    C1[1][nt] = C1[0][nt];
  }
  for (int kc = 0; kc < 4; kc++) {
#pragma unroll
    for (int nt = 0; nt < 8; nt++) {
      short8 bh = *(const short8*)(W0hi + (size_t)(nt * 16 + l15) * 128 + kc * 32 + q * 8);
      short8 bo = *(const short8*)(W0lo + (size_t)(nt * 16 + l15) * 128 + kc * 32 + q * 8);
      C1[0][nt] = MFMA16(Ar[0][kc], bh, C1[0][nt]);
      C1[1][nt] = MFMA16(Ar[1][kc], bh, C1[1][nt]);
      C1[0][nt] = MFMA16(Ar[0][kc], bo, C1[0][nt]);
      C1[1][nt] = MFMA16(Ar[1][kc], bo, C1[1][nt]);
    }
  }
#pragma unroll
  for (int s = 0; s < 2; s++)
#pragma unroll
    for (int nt = 0; nt < 8; nt++)
#pragma unroll
      for (int r = 0; r < 4; r++)
        m2[(wrow + s * 16 + q * 4 + r) * 136 + nt * 16 + l15] =
            f32_to_bf16(fmaxf(C1[s][nt][r], 0.f));
  __syncthreads();

  // phase 2: h' = m2 @ W1 + H @ WSlo + bse
  short8 Am[2][4];
#pragma unroll
  for (int s = 0; s < 2; s++)
#pragma unroll
    for (int kc = 0; kc < 4; kc++)
      Am[s][kc] = *(const short8*)(&m2[(wrow + s * 16 + l15) * 136 + kc * 32 + q * 8]);
  f32x4 C2[2][8];
#pragma unroll
  for (int nt = 0; nt < 8; nt++) {
    float bv = bse[b * 128 + nt * 16 + l15];
    C2[0][nt] = (f32x4){bv, bv, bv, bv};
    C2[1][nt] = C2[0][nt];
  }
  for (int kc = 0; kc < 4; kc++) {
#pragma unroll
    for (int nt = 0; nt < 8; nt++) {
      short8 w1h = *(const short8*)(W1hi + (size_t)(nt * 16 + l15) * 128 + kc * 32 + q * 8);
      short8 w1l = *(const short8*)(W1lo + (size_t)(nt * 16 + l15) * 128 + kc * 32 + q * 8);
      short8 wsh = *(const short8*)(WShi + (size_t)(nt * 16 + l15) * 128 + kc * 32 + q * 8);
      short8 wsl = *(const short8*)(WSlo + (size_t)(nt * 16 + l15) * 128 + kc * 32 + q * 8);
      C2[0][nt] = MFMA16(Am[0][kc], w1h, C2[0][nt]);
      C2[1][nt] = MFMA16(Am[1][kc], w1h, C2[1][nt]);
      C2[0][nt] = MFMA16(Am[0][kc], w1l, C2[0][nt]);
      C2[1][nt] = MFMA16(Am[1][kc], w1l, C2[1][nt]);
      C2[0][nt] = MFMA16(Ah[0][kc], wsh, C2[0][nt]);
      C2[1][nt] = MFMA16(Ah[1][kc], wsh, C2[1][nt]);
      C2[0][nt] = MFMA16(Ah[0][kc], wsl, C2[0][nt]);
      C2[1][nt] = MFMA16(Ah[1][kc], wsl, C2[1][nt]);
    }
  }
  __syncthreads();
#pragma unroll
  for (int s = 0; s < 2; s++)
#pragma unroll
    for (int nt = 0; nt < 8; nt++)
#pragma unroll
      for (int r = 0; r < 4; r++)
        m2[(wrow + s * 16 + q * 4 + r) * 136 + nt * 16 + l15] =
            f32_to_bf16(C2[s][nt][r]);
  __syncthreads();
  {
    int r = tid >> 1, off = (tid & 1) * 64;
#pragma unroll
    for (int i = 0; i < 8; i++) {
      short8 v = *(const short8*)(&m2[r * 136 + off + i * 8]);
      *(short8*)(hout + (size_t)(rowBase + r) * 128 + off + i * 8) = v;
    }
  }
  if (doPool && tid < 128) {
    float v = -1e30f;
    for (int r = 0; r < 128; r++) v = fmaxf(v, bf16_to_f32(m2[r * 136 + tid]));
    pmax[(size_t)blockIdx.x * 128 + tid] = v;
  }
}

// ---------------- scatter-add into transposed plane layout -----------------
__global__ __launch_bounds__(256) void scatter_kernel(
    const float* __restrict__ p, const unsigned short* __restrict__ c,
    float* __restrict__ out, float* __restrict__ cnt) {
  int g = blockIdx.x * 256 + threadIdx.x;
  int b = g >> 16;
  float p0 = p[3 * (size_t)g], p2 = p[3 * (size_t)g + 2];
  float x = p0 / 1.101f + 0.5f;
  x = fminf(fmaxf(x, 0.0f), 1.0f - 1e-6f);
  int xi = (int)(x * 128.0f);
  float z = p2 / 1.101f + 0.5f;
  z = fminf(fmaxf(z, 0.0f), 1.0f - 1e-6f);
  int zi = (int)(z * 128.0f);
  int idx = xi + 128 * zi;
  atomicAdd(cnt + b * NBINS + idx, 1.0f);
  float* ob = out + (size_t)b * HD * NBINS + idx;
  const unsigned short* cr = c + (size_t)g * HD;
  for (int ch = 0; ch < HD; ch++)
    atomicAdd(ob + (size_t)ch * NBINS, bf16_to_f32(cr[ch]));
}

// ---------------- normalize ------------------------------------------------
__global__ void norm_kernel(float* __restrict__ out,
                            const float* __restrict__ cnt) {
  int e = blockIdx.x * 256 + threadIdx.x;
  int b = e >> 21;
  int idx = e & (NBINS - 1);
  out[e] = out[e] / fmaxf(cnt[b * NBINS + idx], 1.0f);
}

extern "C" void kernel_launch(void* const* d_in, const int* in_sizes, int n_in,
                              void* d_out, int out_size, void* d_ws,
                              size_t ws_size, hipStream_t stream) {
  const float* p   = (const float*)d_in[0];
  const float* fcw = (const float*)d_in[1];
  const float* fcb = (const float*)d_in[2];
  const float* w0  = (const float*)d_in[3];
  const float* b0  = (const float*)d_in[4];
  const float* w1  = (const float*)d_in[5];
  const float* b1  = (const float*)d_in[6];
  const float* wsc = (const float*)d_in[7];
  float* out = (float*)d_out;

  char* wsp = (char*)d_ws;
  unsigned short* hA = (unsigned short*)wsp;
  unsigned short* hB = hA + (size_t)G_ALL * HD;
  float* pmax = (float*)(hB + (size_t)G_ALL * HD);    // [2048][128]
  float* b0e = pmax + 2048 * 128;                     // [4][2][128]
  float* bse = b0e + 1024;
  float* Sp  = bse + 1024;                            // [3][128]
  float* bsp = Sp + 384;                              // [128]
  float* cnt = bsp + 128;                             // [2][16384]
  unsigned short* B0hi = (unsigned short*)(cnt + 2 * NBINS);
  unsigned short* B0lo = B0hi + 32768;
  unsigned short* W0hi = B0lo + 32768;   // [4][128][128]
  unsigned short* W0lo = W0hi + 65536;
  unsigned short* W1hi = W0lo + 65536;   // [5][128][128]
  unsigned short* W1lo = W1hi + 81920;
  unsigned short* WShi = W1lo + 81920;   // [4][128][128]
  unsigned short* WSlo = WShi + 65536;

  hipMemsetAsync(d_out, 0, (size_t)2 * HD * NBINS * sizeof(float), stream);
  prep_kernel<<<1, 128, 0, stream>>>(fcw, fcb, wsc, Sp, bsp, cnt);
  wprep_kernel<<<960, 256, 0, stream>>>(w0, w1, wsc, B0hi, B0lo, W0hi, W0lo,
                                        W1hi, W1lo, WShi, WSlo);
  stage0_kernel<<<2048, 256, 0, stream>>>(p, fcw, fcb, B0hi, B0lo, W1hi, W1lo,
                                          b0, b1, Sp, bsp, hA, pmax);
  unsigned short* hin = hA;
  unsigned short* hout = hB;
  for (int s = 1; s < 5; s++) {
    fold_kernel<<<1, 256, 0, stream>>>(
        pmax, (s == 1) ? 1024 : 512, b0 + s * HD, b1 + s * HD,
        w0 + (size_t)(s * 256 + 128) * HD, wsc + (size_t)(s * 256 + 128) * HD,
        b0e + (s - 1) * 256, bse + (s - 1) * 256);
    stageN_kernel<<<1024, 256, 0, stream>>>(
        hin, hout, W0hi + (s - 1) * 16384, W0lo + (s - 1) * 16384,
        W1hi + s * 16384, W1lo + s * 16384, WShi + (s - 1) * 16384,
        WSlo + (s - 1) * 16384, b0e + (s - 1) * 256, bse + (s - 1) * 256,
        pmax, (s < 4) ? 1 : 0);
    unsigned short* t = hin; hin = hout; hout = t;
  }
  scatter_kernel<<<512, 256, 0, stream>>>(p, hin, out, cnt);
  norm_kernel<<<16384, 256, 0, stream>>>(out, cnt);
}

// Round 3
// 1037.775 us; speedup vs baseline: 12.8524x; 2.0385x over previous
//
#include <hip/hip_runtime.h>
#include <hip/hip_bf16.h>

// LocalResnetPointnet v3: barrier-free MFMA stages (per-wave LDS tiles),
// atomicMax pooling, sort-based scatter-mean (index/scan/fill/gather).

#define G_ALL 131072   // B*T
#define HD    128
#define NBINS 16384

typedef __attribute__((ext_vector_type(8))) short short8;
typedef __attribute__((ext_vector_type(4))) float f32x4;

#define MFMA16(a, b, c) __builtin_amdgcn_mfma_f32_16x16x32_bf16(a, b, c, 0, 0, 0)

__device__ __forceinline__ float bf16_to_f32(unsigned short u) {
  union { unsigned int u; float f; } v; v.u = ((unsigned int)u) << 16; return v.f;
}
__device__ __forceinline__ unsigned short f32_to_bf16(float f) {
  union { float f; unsigned int u; } v; v.f = f;
  unsigned int u = v.u;
  u += 0x7fffu + ((u >> 16) & 1u);   // RNE (no NaNs in this workload)
  return (unsigned short)(u >> 16);
}
// order-preserving float -> uint key for atomicMax
__device__ __forceinline__ unsigned int f32_key(float f) {
  union { float f; unsigned int u; } v; v.f = f;
  return (v.u & 0x80000000u) ? ~v.u : (v.u | 0x80000000u);
}
__device__ __forceinline__ float key_f32(unsigned int k) {
  union { unsigned int u; float f; } v;
  v.u = (k & 0x80000000u) ? (k & 0x7fffffffu) : ~k;
  return v.f;
}
__device__ __forceinline__ int bin_of(float p0, float p2) {
  float x = p0 / 1.101f + 0.5f;
  x = fminf(fmaxf(x, 0.0f), 1.0f - 1e-6f);
  int xi = (int)(x * 128.0f);
  float z = p2 / 1.101f + 0.5f;
  z = fminf(fmaxf(z, 0.0f), 1.0f - 1e-6f);
  int zi = (int)(z * 128.0f);
  return xi + 128 * zi;
}

// ---------------- prep: Sp = fcw@ws0, bsp = fcb@ws0, zero pools+hist -------
__global__ void prep_kernel(const float* __restrict__ fcw,
                            const float* __restrict__ fcb,
                            const float* __restrict__ ws0,
                            float* __restrict__ Sp, float* __restrict__ bsp,
                            unsigned int* __restrict__ pool,
                            int* __restrict__ hist) {
  int j = threadIdx.x;  // 128 threads
  for (int d = 0; d < 3; d++) {
    float s = 0.f;
    for (int ch = 0; ch < 256; ch++)
      s = fmaf(fcw[d * 256 + ch], ws0[ch * HD + j], s);
    Sp[d * HD + j] = s;
  }
  float s = 0.f;
  for (int ch = 0; ch < 256; ch++)
    s = fmaf(fcb[ch], ws0[ch * HD + j], s);
  bsp[j] = s;
  for (int k = j; k < 4 * 2 * 128; k += 128) pool[k] = 0u;
  for (int k = j; k < 2 * NBINS; k += 128) hist[k] = 0;
}

// ---------------- weight transform: transpose + bf16 hi/lo split -----------
__global__ void wprep_kernel(const float* __restrict__ w0,
                             const float* __restrict__ w1,
                             const float* __restrict__ ws,
                             unsigned short* __restrict__ B0hi, unsigned short* __restrict__ B0lo,
                             unsigned short* __restrict__ W0hi, unsigned short* __restrict__ W0lo,
                             unsigned short* __restrict__ W1hi, unsigned short* __restrict__ W1lo,
                             unsigned short* __restrict__ WShi, unsigned short* __restrict__ WSlo) {
  int gid = blockIdx.x * 256 + threadIdx.x;
  float v;
  unsigned short *hi, *lo;
  int dst;
  if (gid < 32768) {                       // B0t: [n][k] from w0[0] (256x128)
    int n = gid >> 8, k = gid & 255;
    v = w0[k * 128 + n];
    hi = B0hi; lo = B0lo; dst = gid;
  } else if (gid < 98304) {                // W0t stages 1..4, rows 0..127
    int i = gid - 32768; int s = i >> 14; int n = (i >> 7) & 127; int k = i & 127;
    v = w0[(size_t)((s + 1) * 256 + k) * 128 + n];
    hi = W0hi; lo = W0lo; dst = i;
  } else if (gid < 180224) {               // W1t stages 0..4
    int i = gid - 98304; int s = i >> 14; int n = (i >> 7) & 127; int k = i & 127;
    v = w1[(size_t)(s * 128 + k) * 128 + n];
    hi = W1hi; lo = W1lo; dst = i;
  } else if (gid < 245760) {               // WSt stages 1..4, rows 0..127
    int i = gid - 180224; int s = i >> 14; int n = (i >> 7) & 127; int k = i & 127;
    v = ws[(size_t)((s + 1) * 256 + k) * 128 + n];
    hi = WShi; lo = WSlo; dst = i;
  } else return;
  unsigned short h = f32_to_bf16(v);
  hi[dst] = h;
  lo[dst] = f32_to_bf16(v - bf16_to_f32(h));
}

// ---------------- scatter pipeline -----------------------------------------
__global__ __launch_bounds__(256) void index_kernel(const float* __restrict__ p,
                                                    int* __restrict__ hist) {
  int g = blockIdx.x * 256 + threadIdx.x;
  int b = g >> 16;
  int idx = bin_of(p[3 * (size_t)g], p[3 * (size_t)g + 2]);
  atomicAdd(&hist[b * NBINS + idx], 1);
}

__global__ __launch_bounds__(1024) void scan_kernel(int* __restrict__ hist,
                                                    int* __restrict__ offsets) {
  __shared__ int sd[1024];
  int t = threadIdx.x;
  int vals[32];
  int s = 0;
#pragma unroll
  for (int i = 0; i < 32; i++) { vals[i] = hist[t * 32 + i]; s += vals[i]; }
  sd[t] = s;
  __syncthreads();
  for (int d = 1; d < 1024; d <<= 1) {
    int v = (t >= d) ? sd[t - d] : 0;
    __syncthreads();
    sd[t] += v;
    __syncthreads();
  }
  int run = sd[t] - s;  // exclusive prefix
#pragma unroll
  for (int i = 0; i < 32; i++) {
    offsets[t * 32 + i] = run;
    hist[t * 32 + i] = run;  // cursor copy (in-place)
    run += vals[i];
  }
  if (t == 1023) offsets[32768] = run;  // sentinel = G_ALL
}

__global__ __launch_bounds__(256) void fill_kernel(const float* __restrict__ p,
                                                   int* __restrict__ cursor,
                                                   int* __restrict__ order) {
  int g = blockIdx.x * 256 + threadIdx.x;
  int b = g >> 16;
  int idx = bin_of(p[3 * (size_t)g], p[3 * (size_t)g + 2]);
  int pos = atomicAdd(&cursor[b * NBINS + idx], 1);
  order[pos] = g;
}

// gather + mean: one wave per 16 bins; writes EVERY output element.
__global__ __launch_bounds__(256) void gather_kernel(
    const unsigned short* __restrict__ c, const int* __restrict__ offsets,
    const int* __restrict__ order, float* __restrict__ out) {
  int wave = threadIdx.x >> 6, lane = threadIdx.x & 63;
  int b = blockIdx.x >> 8;
  int binBase = (blockIdx.x & 255) * 64 + wave * 16;
  for (int bi = 0; bi < 16; bi++) {
    int B = b * NBINS + binBase + bi;
    int st = offsets[B], en = offsets[B + 1];
    float a0 = 0.f, a1 = 0.f;
    for (int k = st; k < en; k++) {
      int g = order[k];
      unsigned int u = *(const unsigned int*)(c + (size_t)g * HD + lane * 2);
      a0 += bf16_to_f32((unsigned short)(u & 0xffffu));
      a1 += bf16_to_f32((unsigned short)(u >> 16));
    }
    float cf = fmaxf((float)(en - st), 1.0f);
    size_t base = (size_t)b * HD * NBINS + (size_t)(binBase + bi);
    out[base + (size_t)(2 * lane) * NBINS] = a0 / cf;
    out[base + (size_t)(2 * lane + 1) * NBINS] = a1 / cf;
  }
}

// ---------------- stage 0: fc_pos + block0 (MFMA, barrier-free) ------------
// block = 4 waves x 16 rows = 64 points.
__global__ __launch_bounds__(256) void stage0_kernel(
    const float* __restrict__ p, const float* __restrict__ fcw,
    const float* __restrict__ fcb,
    const unsigned short* __restrict__ B0hi, const unsigned short* __restrict__ B0lo,
    const unsigned short* __restrict__ W1hi, const unsigned short* __restrict__ W1lo,
    const float* __restrict__ b0, const float* __restrict__ b1,
    const float* __restrict__ Sp, const float* __restrict__ bsp,
    unsigned short* __restrict__ hout, unsigned int* __restrict__ pool) {
  __shared__ float pt[4][16 * 4];
  __shared__ unsigned short x0t[4][16 * 264];
  __shared__ unsigned short m2[4][16 * 136];
  const int tid = threadIdx.x;
  const int wave = tid >> 6, lane = tid & 63;
  const int q = lane >> 4, l15 = lane & 15;
  const int rowBase = blockIdx.x * 64 + wave * 16;
  const int b = blockIdx.x >> 10;
  float* ptw = pt[wave];
  unsigned short* xw = x0t[wave];
  unsigned short* mw = m2[wave];

  if (lane < 48) ptw[(lane / 3) * 4 + (lane % 3)] = p[(size_t)rowBase * 3 + lane];
  {
    int row = lane >> 2, c0 = (lane & 3) * 64;
    float p0 = ptw[row * 4], p1 = ptw[row * 4 + 1], p2 = ptw[row * 4 + 2];
    for (int cc = 0; cc < 64; cc++) {
      int cch = c0 + cc;
      float x = fcb[cch] + p0 * fcw[cch] + p1 * fcw[256 + cch] + p2 * fcw[512 + cch];
      xw[row * 264 + cch] = f32_to_bf16(fmaxf(x, 0.f));
    }
  }

  // phase 1: net = relu(x0) @ W0[0] + b0[0]   (K = 256)
  short8 Ar[8];
#pragma unroll
  for (int kc = 0; kc < 8; kc++)
    Ar[kc] = *(const short8*)(&xw[l15 * 264 + kc * 32 + q * 8]);
  f32x4 C[8];
#pragma unroll
  for (int nt = 0; nt < 8; nt++) {
    float bv = b0[nt * 16 + l15];
    C[nt] = (f32x4){bv, bv, bv, bv};
  }
  for (int kc = 0; kc < 8; kc++) {
#pragma unroll
    for (int nt = 0; nt < 8; nt++) {
      short8 bh = *(const short8*)(B0hi + (size_t)(nt * 16 + l15) * 256 + kc * 32 + q * 8);
      short8 bo = *(const short8*)(B0lo + (size_t)(nt * 16 + l15) * 256 + kc * 32 + q * 8);
      C[nt] = MFMA16(Ar[kc], bh, C[nt]);
      C[nt] = MFMA16(Ar[kc], bo, C[nt]);
    }
  }
#pragma unroll
  for (int nt = 0; nt < 8; nt++)
#pragma unroll
    for (int r = 0; r < 4; r++)
      mw[(q * 4 + r) * 136 + nt * 16 + l15] = f32_to_bf16(fmaxf(C[nt][r], 0.f));

  // phase 2: h = m2 @ W1[0] + (p @ Sp + bsp + b1[0])
  short8 Am[4];
#pragma unroll
  for (int kc = 0; kc < 4; kc++)
    Am[kc] = *(const short8*)(&mw[l15 * 136 + kc * 32 + q * 8]);
  f32x4 C2[8];
#pragma unroll
  for (int nt = 0; nt < 8; nt++) {
    int cch = nt * 16 + l15;
    float bb = bsp[cch] + b1[cch];
    float s0 = Sp[cch], s1 = Sp[128 + cch], s2 = Sp[256 + cch];
#pragma unroll
    for (int r = 0; r < 4; r++) {
      int row = q * 4 + r;
      C2[nt][r] = bb + ptw[row * 4] * s0 + ptw[row * 4 + 1] * s1 + ptw[row * 4 + 2] * s2;
    }
  }
  for (int kc = 0; kc < 4; kc++) {
#pragma unroll
    for (int nt = 0; nt < 8; nt++) {
      short8 bh = *(const short8*)(W1hi + (size_t)(nt * 16 + l15) * 128 + kc * 32 + q * 8);
      short8 bo = *(const short8*)(W1lo + (size_t)(nt * 16 + l15) * 128 + kc * 32 + q * 8);
      C2[nt] = MFMA16(Am[kc], bh, C2[nt]);
      C2[nt] = MFMA16(Am[kc], bo, C2[nt]);
    }
  }
#pragma unroll
  for (int nt = 0; nt < 8; nt++)
#pragma unroll
    for (int r = 0; r < 4; r++)
      mw[(q * 4 + r) * 136 + nt * 16 + l15] = f32_to_bf16(C2[nt][r]);
  // pool (stage0 always pools)
#pragma unroll
  for (int nt = 0; nt < 8; nt++) {
    float m = fmaxf(fmaxf(C2[nt][0], C2[nt][1]), fmaxf(C2[nt][2], C2[nt][3]));
    m = fmaxf(m, __shfl_xor(m, 16, 64));
    m = fmaxf(m, __shfl_xor(m, 32, 64));
    if (lane < 16) atomicMax(&pool[b * 128 + nt * 16 + lane], f32_key(m));
  }
  // write out 16 rows per wave
#pragma unroll
  for (int i = 0; i < 4; i++) {
    int row = i * 4 + q;
    short8 v = *(const short8*)(&mw[row * 136 + l15 * 8]);
    *(short8*)(hout + (size_t)(rowBase + row) * 128 + l15 * 8) = v;
  }
}

// ---------------- stages 1..4 (MFMA, barrier-free) -------------------------
// block = 4 waves x 32 rows = 128 points.
__global__ __launch_bounds__(256) void stageN_kernel(
    const unsigned short* __restrict__ hin, unsigned short* __restrict__ hout,
    const unsigned short* __restrict__ W0hi, const unsigned short* __restrict__ W0lo,
    const unsigned short* __restrict__ W1hi, const unsigned short* __restrict__ W1lo,
    const unsigned short* __restrict__ WShi, const unsigned short* __restrict__ WSlo,
    const float* __restrict__ b0e, const float* __restrict__ bse,
    unsigned int* __restrict__ pool, int doPool) {
  __shared__ unsigned short m2[4][32 * 136];
  const int tid = threadIdx.x;
  const int wave = tid >> 6, lane = tid & 63;
  const int q = lane >> 4, l15 = lane & 15;
  const int rowBase = blockIdx.x * 128 + wave * 32;
  const int b = blockIdx.x >> 9;
  unsigned short* mw = m2[wave];

  short8 Ah[2][4], Ar[2][4];
#pragma unroll
  for (int s = 0; s < 2; s++)
#pragma unroll
    for (int kc = 0; kc < 4; kc++) {
      int m = rowBase + s * 16 + l15;
      Ah[s][kc] = *(const short8*)(hin + (size_t)m * 128 + kc * 32 + q * 8);
    }
#pragma unroll
  for (int s = 0; s < 2; s++)
#pragma unroll
    for (int kc = 0; kc < 4; kc++)
#pragma unroll
      for (int e = 0; e < 8; e++)
        Ar[s][kc][e] = Ah[s][kc][e] < 0 ? (short)0 : Ah[s][kc][e];

  // phase 1: net = relu(H) @ W0 + b0e
  f32x4 C1[2][8];
#pragma unroll
  for (int nt = 0; nt < 8; nt++) {
    float bv = b0e[b * 128 + nt * 16 + l15];
    C1[0][nt] = (f32x4){bv, bv, bv, bv};
    C1[1][nt] = C1[0][nt];
  }
  for (int kc = 0; kc < 4; kc++) {
#pragma unroll
    for (int nt = 0; nt < 8; nt++) {
      short8 bh = *(const short8*)(W0hi + (size_t)(nt * 16 + l15) * 128 + kc * 32 + q * 8);
      short8 bo = *(const short8*)(W0lo + (size_t)(nt * 16 + l15) * 128 + kc * 32 + q * 8);
      C1[0][nt] = MFMA16(Ar[0][kc], bh, C1[0][nt]);
      C1[1][nt] = MFMA16(Ar[1][kc], bh, C1[1][nt]);
      C1[0][nt] = MFMA16(Ar[0][kc], bo, C1[0][nt]);
      C1[1][nt] = MFMA16(Ar[1][kc], bo, C1[1][nt]);
    }
  }
#pragma unroll
  for (int s = 0; s < 2; s++)
#pragma unroll
    for (int nt = 0; nt < 8; nt++)
#pragma unroll
      for (int r = 0; r < 4; r++)
        mw[(s * 16 + q * 4 + r) * 136 + nt * 16 + l15] =
            f32_to_bf16(fmaxf(C1[s][nt][r], 0.f));

  // phase 2: h' = m2 @ W1 + H @ WS + bse
  short8 Am[2][4];
#pragma unroll
  for (int s = 0; s < 2; s++)
#pragma unroll
    for (int kc = 0; kc < 4; kc++)
      Am[s][kc] = *(const short8*)(&mw[(s * 16 + l15) * 136 + kc * 32 + q * 8]);
  f32x4 C2[2][8];
#pragma unroll
  for (int nt = 0; nt < 8; nt++) {
    float bv = bse[b * 128 + nt * 16 + l15];
    C2[0][nt] = (f32x4){bv, bv, bv, bv};
    C2[1][nt] = C2[0][nt];
  }
  for (int kc = 0; kc < 4; kc++) {
#pragma unroll
    for (int nt = 0; nt < 8; nt++) {
      short8 w1h = *(const short8*)(W1hi + (size_t)(nt * 16 + l15) * 128 + kc * 32 + q * 8);
      short8 w1l = *(const short8*)(W1lo + (size_t)(nt * 16 + l15) * 128 + kc * 32 + q * 8);
      short8 wsh = *(const short8*)(WShi + (size_t)(nt * 16 + l15) * 128 + kc * 32 + q * 8);
      short8 wsl = *(const short8*)(WSlo + (size_t)(nt * 16 + l15) * 128 + kc * 32 + q * 8);
      C2[0][nt] = MFMA16(Am[0][kc], w1h, C2[0][nt]);
      C2[1][nt] = MFMA16(Am[1][kc], w1h, C2[1][nt]);
      C2[0][nt] = MFMA16(Am[0][kc], w1l, C2[0][nt]);
      C2[1][nt] = MFMA16(Am[1][kc], w1l, C2[1][nt]);
      C2[0][nt] = MFMA16(Ah[0][kc], wsh, C2[0][nt]);
      C2[1][nt] = MFMA16(Ah[1][kc], wsh, C2[1][nt]);
      C2[0][nt] = MFMA16(Ah[0][kc], wsl, C2[0][nt]);
      C2[1][nt] = MFMA16(Ah[1][kc], wsl, C2[1][nt]);
    }
  }
#pragma unroll
  for (int s = 0; s < 2; s++)
#pragma unroll
    for (int nt = 0; nt < 8; nt++)
#pragma unroll
      for (int r = 0; r < 4; r++)
        mw[(s * 16 + q * 4 + r) * 136 + nt * 16 + l15] = f32_to_bf16(C2[s][nt][r]);
  if (doPool) {
#pragma unroll
    for (int nt = 0; nt < 8; nt++) {
      float m = -1e30f;
#pragma unroll
      for (int s = 0; s < 2; s++)
#pragma unroll
        for (int r = 0; r < 4; r++) m = fmaxf(m, C2[s][nt][r]);
      m = fmaxf(m, __shfl_xor(m, 16, 64));
      m = fmaxf(m, __shfl_xor(m, 32, 64));
      if (lane < 16) atomicMax(&pool[b * 128 + nt * 16 + lane], f32_key(m));
    }
  }
  // write out 32 rows per wave
#pragma unroll
  for (int i = 0; i < 8; i++) {
    int row = i * 4 + q;
    short8 v = *(const short8*)(&mw[row * 136 + l15 * 8]);
    *(short8*)(hout + (size_t)(rowBase + row) * 128 + l15 * 8) = v;
  }
}

// ---------------- fold: per-batch effective biases from pool ---------------
__global__ void fold_kernel(const unsigned int* __restrict__ pool,
                            const float* __restrict__ b0s,
                            const float* __restrict__ b1s,
                            const float* __restrict__ w0hi,  // f32, rows 128..255
                            const float* __restrict__ wshi,
                            float* __restrict__ b0e, float* __restrict__ bse) {
  __shared__ float ps[256];
  int tid = threadIdx.x;  // 256
  int b = tid >> 7, j = tid & 127;
  ps[tid] = key_f32(pool[tid]);
  __syncthreads();
  float a0 = b0s[j], a1 = b1s[j];
  for (int ch = 0; ch < 128; ch++) {
    float pv = ps[b * 128 + ch];
    a0 = fmaf(fmaxf(pv, 0.f), w0hi[ch * HD + j], a0);
    a1 = fmaf(pv, wshi[ch * HD + j], a1);
  }
  b0e[b * 128 + j] = a0;
  bse[b * 128 + j] = a1;
}

extern "C" void kernel_launch(void* const* d_in, const int* in_sizes, int n_in,
                              void* d_out, int out_size, void* d_ws,
                              size_t ws_size, hipStream_t stream) {
  const float* p   = (const float*)d_in[0];
  const float* fcw = (const float*)d_in[1];
  const float* fcb = (const float*)d_in[2];
  const float* w0  = (const float*)d_in[3];
  const float* b0  = (const float*)d_in[4];
  const float* w1  = (const float*)d_in[5];
  const float* b1  = (const float*)d_in[6];
  const float* wsc = (const float*)d_in[7];
  float* out = (float*)d_out;

  char* wsp = (char*)d_ws;
  unsigned short* hA = (unsigned short*)wsp;
  unsigned short* hB = hA + (size_t)G_ALL * HD;
  unsigned short* B0hi = hB + (size_t)G_ALL * HD;
  unsigned short* B0lo = B0hi + 32768;
  unsigned short* W0hi = B0lo + 32768;   // [4][128][128]
  unsigned short* W0lo = W0hi + 65536;
  unsigned short* W1hi = W0lo + 65536;   // [5][128][128]
  unsigned short* W1lo = W1hi + 81920;
  unsigned short* WShi = W1lo + 81920;   // [4][128][128]
  unsigned short* WSlo = WShi + 65536;
  unsigned int* pool = (unsigned int*)(WSlo + 65536);  // [4][2][128]
  float* b0e = (float*)(pool + 1024);    // [4][2][128]
  float* bse = b0e + 1024;
  float* Sp  = bse + 1024;               // [3][128]
  float* bsp = Sp + 384;                 // [128]
  int* hist    = (int*)(bsp + 128);      // [2][16384] (becomes cursor)
  int* offsets = hist + 2 * NBINS;       // [2*16384 + 1] (+pad)
  int* order   = offsets + 2 * NBINS + 4;  // [131072]

  prep_kernel<<<1, 128, 0, stream>>>(fcw, fcb, wsc, Sp, bsp, pool, hist);
  wprep_kernel<<<960, 256, 0, stream>>>(w0, w1, wsc, B0hi, B0lo, W0hi, W0lo,
                                        W1hi, W1lo, WShi, WSlo);
  index_kernel<<<512, 256, 0, stream>>>(p, hist);
  scan_kernel<<<1, 1024, 0, stream>>>(hist, offsets);
  fill_kernel<<<512, 256, 0, stream>>>(p, hist, order);

  stage0_kernel<<<2048, 256, 0, stream>>>(p, fcw, fcb, B0hi, B0lo, W1hi, W1lo,
                                          b0, b1, Sp, bsp, hA, pool);
  unsigned short* hin = hA;
  unsigned short* hout = hB;
  for (int s = 1; s < 5; s++) {
    fold_kernel<<<1, 256, 0, stream>>>(
        pool + (s - 1) * 256, b0 + s * HD, b1 + s * HD,
        w0 + (size_t)(s * 256 + 128) * HD, wsc + (size_t)(s * 256 + 128) * HD,
        b0e + (s - 1) * 256, bse + (s - 1) * 256);
    stageN_kernel<<<1024, 256, 0, stream>>>(
        hin, hout, W0hi + (s - 1) * 16384, W0lo + (s - 1) * 16384,
        W1hi + s * 16384, W1lo + s * 16384, WShi + (s - 1) * 16384,
        WSlo + (s - 1) * 16384, b0e + (s - 1) * 256, bse + (s - 1) * 256,
        pool + s * 256, (s < 4) ? 1 : 0);
    unsigned short* t = hin; hin = hout; hout = t;
  }
  gather_kernel<<<512, 256, 0, stream>>>(hin, offsets, order, out);
}

// Round 4
// 535.263 us; speedup vs baseline: 24.9184x; 1.9388x over previous
//
#include <hip/hip_runtime.h>
#include <hip/hip_bf16.h>

// LocalResnetPointnet v4: weight-stationary MFMA stages (weights in VGPRs,
// one nt-slice per wave, 8-wave blocks looping over row tiles), sort-based
// scatter-mean (index/scan/fill/gather).

#define G_ALL 131072   // B*T
#define HD    128
#define NBINS 16384

typedef __attribute__((ext_vector_type(8))) short short8;
typedef __attribute__((ext_vector_type(4))) float f32x4;

#define MFMA16(a, b, c) __builtin_amdgcn_mfma_f32_16x16x32_bf16(a, b, c, 0, 0, 0)

__device__ __forceinline__ float bf16_to_f32(unsigned short u) {
  union { unsigned int u; float f; } v; v.u = ((unsigned int)u) << 16; return v.f;
}
__device__ __forceinline__ unsigned short f32_to_bf16(float f) {
  union { float f; unsigned int u; } v; v.f = f;
  unsigned int u = v.u;
  u += 0x7fffu + ((u >> 16) & 1u);   // RNE (no NaNs in this workload)
  return (unsigned short)(u >> 16);
}
// order-preserving float -> uint key for atomicMax
__device__ __forceinline__ unsigned int f32_key(float f) {
  union { float f; unsigned int u; } v; v.f = f;
  return (v.u & 0x80000000u) ? ~v.u : (v.u | 0x80000000u);
}
__device__ __forceinline__ float key_f32(unsigned int k) {
  union { unsigned int u; float f; } v;
  v.u = (k & 0x80000000u) ? (k & 0x7fffffffu) : ~k;
  return v.f;
}
__device__ __forceinline__ int bin_of(float p0, float p2) {
  float x = p0 / 1.101f + 0.5f;
  x = fminf(fmaxf(x, 0.0f), 1.0f - 1e-6f);
  int xi = (int)(x * 128.0f);
  float z = p2 / 1.101f + 0.5f;
  z = fminf(fmaxf(z, 0.0f), 1.0f - 1e-6f);
  int zi = (int)(z * 128.0f);
  return xi + 128 * zi;
}
__device__ __forceinline__ short8 relu8(short8 a) {
  short8 r;
#pragma unroll
  for (int e = 0; e < 8; e++) r[e] = a[e] < 0 ? (short)0 : a[e];
  return r;
}

// ---------------- prep: Sp = fcw@ws0, bsp = fcb@ws0, zero pools+hist -------
__global__ void prep_kernel(const float* __restrict__ fcw,
                            const float* __restrict__ fcb,
                            const float* __restrict__ ws0,
                            float* __restrict__ Sp, float* __restrict__ bsp,
                            unsigned int* __restrict__ pool,
                            int* __restrict__ hist) {
  int j = threadIdx.x;  // 128 threads
  for (int d = 0; d < 3; d++) {
    float s = 0.f;
    for (int ch = 0; ch < 256; ch++)
      s = fmaf(fcw[d * 256 + ch], ws0[ch * HD + j], s);
    Sp[d * HD + j] = s;
  }
  float s = 0.f;
  for (int ch = 0; ch < 256; ch++)
    s = fmaf(fcb[ch], ws0[ch * HD + j], s);
  bsp[j] = s;
  for (int k = j; k < 4 * 2 * 128; k += 128) pool[k] = 0u;
  for (int k = j; k < 2 * NBINS; k += 128) hist[k] = 0;
}

// ---------------- weight transform: transpose + bf16 hi/lo split -----------
__global__ void wprep_kernel(const float* __restrict__ w0,
                             const float* __restrict__ w1,
                             const float* __restrict__ ws,
                             unsigned short* __restrict__ B0hi, unsigned short* __restrict__ B0lo,
                             unsigned short* __restrict__ W0hi, unsigned short* __restrict__ W0lo,
                             unsigned short* __restrict__ W1hi, unsigned short* __restrict__ W1lo,
                             unsigned short* __restrict__ WShi, unsigned short* __restrict__ WSlo) {
  int gid = blockIdx.x * 256 + threadIdx.x;
  float v;
  unsigned short *hi, *lo;
  int dst;
  if (gid < 32768) {                       // B0t: [n][k] from w0[0] (256x128)
    int n = gid >> 8, k = gid & 255;
    v = w0[k * 128 + n];
    hi = B0hi; lo = B0lo; dst = gid;
  } else if (gid < 98304) {                // W0t stages 1..4, rows 0..127
    int i = gid - 32768; int s = i >> 14; int n = (i >> 7) & 127; int k = i & 127;
    v = w0[(size_t)((s + 1) * 256 + k) * 128 + n];
    hi = W0hi; lo = W0lo; dst = i;
  } else if (gid < 180224) {               // W1t stages 0..4
    int i = gid - 98304; int s = i >> 14; int n = (i >> 7) & 127; int k = i & 127;
    v = w1[(size_t)(s * 128 + k) * 128 + n];
    hi = W1hi; lo = W1lo; dst = i;
  } else if (gid < 245760) {               // WSt stages 1..4, rows 0..127
    int i = gid - 180224; int s = i >> 14; int n = (i >> 7) & 127; int k = i & 127;
    v = ws[(size_t)((s + 1) * 256 + k) * 128 + n];
    hi = WShi; lo = WSlo; dst = i;
  } else return;
  unsigned short h = f32_to_bf16(v);
  hi[dst] = h;
  lo[dst] = f32_to_bf16(v - bf16_to_f32(h));
}

// ---------------- scatter pipeline -----------------------------------------
__global__ __launch_bounds__(256) void index_kernel(const float* __restrict__ p,
                                                    int* __restrict__ hist) {
  int g = blockIdx.x * 256 + threadIdx.x;
  int b = g >> 16;
  int idx = bin_of(p[3 * (size_t)g], p[3 * (size_t)g + 2]);
  atomicAdd(&hist[b * NBINS + idx], 1);
}

__global__ __launch_bounds__(1024) void scan_kernel(int* __restrict__ hist,
                                                    int* __restrict__ offsets) {
  __shared__ int sd[1024];
  int t = threadIdx.x;
  int vals[32];
  int s = 0;
#pragma unroll
  for (int i = 0; i < 32; i++) { vals[i] = hist[t * 32 + i]; s += vals[i]; }
  sd[t] = s;
  __syncthreads();
  for (int d = 1; d < 1024; d <<= 1) {
    int v = (t >= d) ? sd[t - d] : 0;
    __syncthreads();
    sd[t] += v;
    __syncthreads();
  }
  int run = sd[t] - s;  // exclusive prefix
#pragma unroll
  for (int i = 0; i < 32; i++) {
    offsets[t * 32 + i] = run;
    hist[t * 32 + i] = run;  // cursor copy (in-place)
    run += vals[i];
  }
  if (t == 1023) offsets[32768] = run;  // sentinel = G_ALL
}

__global__ __launch_bounds__(256) void fill_kernel(const float* __restrict__ p,
                                                   int* __restrict__ cursor,
                                                   int* __restrict__ order) {
  int g = blockIdx.x * 256 + threadIdx.x;
  int b = g >> 16;
  int idx = bin_of(p[3 * (size_t)g], p[3 * (size_t)g + 2]);
  int pos = atomicAdd(&cursor[b * NBINS + idx], 1);
  order[pos] = g;
}

// gather + mean: one wave per 16 bins; writes EVERY output element.
__global__ __launch_bounds__(256) void gather_kernel(
    const unsigned short* __restrict__ c, const int* __restrict__ offsets,
    const int* __restrict__ order, float* __restrict__ out) {
  int wave = threadIdx.x >> 6, lane = threadIdx.x & 63;
  int b = blockIdx.x >> 8;
  int binBase = (blockIdx.x & 255) * 64 + wave * 16;
  for (int bi = 0; bi < 16; bi++) {
    int B = b * NBINS + binBase + bi;
    int st = offsets[B], en = offsets[B + 1];
    float a0 = 0.f, a1 = 0.f;
    for (int k = st; k < en; k++) {
      int g = order[k];
      unsigned int u = *(const unsigned int*)(c + (size_t)g * HD + lane * 2);
      a0 += bf16_to_f32((unsigned short)(u & 0xffffu));
      a1 += bf16_to_f32((unsigned short)(u >> 16));
    }
    float cf = fmaxf((float)(en - st), 1.0f);
    size_t base = (size_t)b * HD * NBINS + (size_t)(binBase + bi);
    out[base + (size_t)(2 * lane) * NBINS] = a0 / cf;
    out[base + (size_t)(2 * lane + 1) * NBINS] = a1 / cf;
  }
}

// ---------------- stage 0: fc_pos + block0 (weight-stationary MFMA) --------
// 8 waves; wave = nt (16 output ch). Block = 128 rows (2 iters x 64 rows).
__global__ __launch_bounds__(512, 2) void stage0_kernel(
    const float* __restrict__ p, const float* __restrict__ fcw,
    const float* __restrict__ fcb,
    const unsigned short* __restrict__ B0hi, const unsigned short* __restrict__ B0lo,
    const unsigned short* __restrict__ W1hi, const unsigned short* __restrict__ W1lo,
    const float* __restrict__ b0, const float* __restrict__ b1,
    const float* __restrict__ Sp, const float* __restrict__ bsp,
    unsigned short* __restrict__ hout, unsigned int* __restrict__ pool) {
  __shared__ float fcL[1024];                // fcw (768) + fcb (256)
  __shared__ float ptL[64 * 4];
  __shared__ unsigned short x0t[64 * 264];   // K=256 relu(fc_pos) tile; reused as out tile
  __shared__ unsigned short m2[64 * 136];
  const int tid = threadIdx.x;
  const int lane = tid & 63;
  const int q = lane >> 4, l15 = lane & 15;
  const int nt = tid >> 6;                   // wave id = output-ch tile
  const int b = blockIdx.x >> 9;
  const int wrow = nt * 16 + l15;

  // weights -> registers (once per kernel)
  short8 b0h[8], b0l[8], w1h[4], w1l[4];
#pragma unroll
  for (int kc = 0; kc < 8; kc++) {
    b0h[kc] = *(const short8*)(B0hi + (size_t)wrow * 256 + kc * 32 + q * 8);
    b0l[kc] = *(const short8*)(B0lo + (size_t)wrow * 256 + kc * 32 + q * 8);
  }
#pragma unroll
  for (int kc = 0; kc < 4; kc++) {
    w1h[kc] = *(const short8*)(W1hi + (size_t)wrow * 128 + kc * 32 + q * 8);
    w1l[kc] = *(const short8*)(W1lo + (size_t)wrow * 128 + kc * 32 + q * 8);
  }
  const float bias1 = b0[wrow];
  const float bias2 = bsp[wrow] + b1[wrow];
  const float sp0 = Sp[wrow], sp1 = Sp[128 + wrow], sp2 = Sp[256 + wrow];

  for (int k = tid; k < 1024; k += 512)
    fcL[k] = (k < 768) ? fcw[k] : fcb[k - 768];

  for (int it = 0; it < 2; it++) {
    const int rowBase = blockIdx.x * 128 + it * 64;
    __syncthreads();  // fcL ready (it0) / prev out-store complete
    if (tid < 192) ptL[(tid / 3) * 4 + (tid % 3)] = p[(size_t)rowBase * 3 + tid];
    __syncthreads();  // ptL ready
    // fc_pos: row = tid>>3, 32 channels per thread
    {
      int row = tid >> 3, c0 = (tid & 7) * 32;
      float p0 = ptL[row * 4], p1 = ptL[row * 4 + 1], p2 = ptL[row * 4 + 2];
#pragma unroll
      for (int j2 = 0; j2 < 4; j2++) {
        short8 v;
#pragma unroll
        for (int e = 0; e < 8; e++) {
          int c = c0 + j2 * 8 + e;
          float x = fcL[768 + c] + p0 * fcL[c] + p1 * fcL[256 + c] + p2 * fcL[512 + c];
          v[e] = (short)f32_to_bf16(fmaxf(x, 0.f));
        }
        *(short8*)(&x0t[row * 264 + c0 + j2 * 8]) = v;
      }
    }
    __syncthreads();  // x0t ready; prev m2 reads long done
    // phase 1: net = relu(x0) @ W0[0] + b0[0]  (K=256)
    f32x4 C1[4];
#pragma unroll
    for (int s = 0; s < 4; s++) C1[s] = (f32x4){bias1, bias1, bias1, bias1};
#pragma unroll
    for (int kc = 0; kc < 8; kc++) {
#pragma unroll
      for (int s = 0; s < 4; s++) {
        short8 Ar = *(const short8*)(&x0t[(s * 16 + l15) * 264 + kc * 32 + q * 8]);
        C1[s] = MFMA16(Ar, b0h[kc], C1[s]);
        C1[s] = MFMA16(Ar, b0l[kc], C1[s]);
      }
    }
#pragma unroll
    for (int s = 0; s < 4; s++)
#pragma unroll
      for (int r = 0; r < 4; r++)
        m2[(s * 16 + q * 4 + r) * 136 + nt * 16 + l15] =
            f32_to_bf16(fmaxf(C1[s][r], 0.f));
    __syncthreads();  // m2 ready; x0t reads done -> reuse as out tile
    // phase 2: h = m2 @ W1[0] + (p @ Sp + bsp + b1[0])
    f32x4 C2[4];
#pragma unroll
    for (int s = 0; s < 4; s++)
#pragma unroll
      for (int r = 0; r < 4; r++) {
        int row = s * 16 + q * 4 + r;
        C2[s][r] = bias2 + ptL[row * 4] * sp0 + ptL[row * 4 + 1] * sp1 +
                   ptL[row * 4 + 2] * sp2;
      }
#pragma unroll
    for (int kc = 0; kc < 4; kc++) {
#pragma unroll
      for (int s = 0; s < 4; s++) {
        short8 Am = *(const short8*)(&m2[(s * 16 + l15) * 136 + kc * 32 + q * 8]);
        C2[s] = MFMA16(Am, w1h[kc], C2[s]);
        C2[s] = MFMA16(Am, w1l[kc], C2[s]);
      }
    }
#pragma unroll
    for (int s = 0; s < 4; s++)
#pragma unroll
      for (int r = 0; r < 4; r++)
        x0t[(s * 16 + q * 4 + r) * 136 + nt * 16 + l15] = f32_to_bf16(C2[s][r]);
    {
      float m = -1e30f;
#pragma unroll
      for (int s = 0; s < 4; s++)
#pragma unroll
        for (int r = 0; r < 4; r++) m = fmaxf(m, C2[s][r]);
      m = fmaxf(m, __shfl_xor(m, 16, 64));
      m = fmaxf(m, __shfl_xor(m, 32, 64));
      if (lane < 16) atomicMax(&pool[b * 128 + nt * 16 + lane], f32_key(m));
    }
    __syncthreads();  // out tile ready
    {
      int r = tid >> 3, cs = (tid & 7) * 16;
      short8 v0 = *(const short8*)(&x0t[r * 136 + cs]);
      short8 v1 = *(const short8*)(&x0t[r * 136 + cs + 8]);
      *(short8*)(hout + (size_t)(rowBase + r) * 128 + cs) = v0;
      *(short8*)(hout + (size_t)(rowBase + r) * 128 + cs + 8) = v1;
    }
  }
}

// ---------------- stages 1..4 (weight-stationary MFMA) ---------------------
// 8 waves; wave = nt. Block = 128 rows (2 iters x 64 rows).
__global__ __launch_bounds__(512, 2) void stageN_kernel(
    const unsigned short* __restrict__ hin, unsigned short* __restrict__ hout,
    const unsigned short* __restrict__ W0hi, const unsigned short* __restrict__ W0lo,
    const unsigned short* __restrict__ W1hi, const unsigned short* __restrict__ W1lo,
    const unsigned short* __restrict__ WShi, const unsigned short* __restrict__ WSlo,
    const float* __restrict__ b0e, const float* __restrict__ bse,
    unsigned int* __restrict__ pool, int doPool) {
  __shared__ unsigned short At[64 * 136];   // H tile (pre-relu)
  __shared__ unsigned short m2[64 * 136];   // relu(net) tile
  __shared__ unsigned short oT[64 * 136];   // output tile
  const int tid = threadIdx.x;
  const int lane = tid & 63;
  const int q = lane >> 4, l15 = lane & 15;
  const int nt = tid >> 6;
  const int b = blockIdx.x >> 9;
  const int wrow = nt * 16 + l15;

  short8 w0h[4], w0l[4], w1h[4], w1l[4], wsh[4], wsl[4];
#pragma unroll
  for (int kc = 0; kc < 4; kc++) {
    w0h[kc] = *(const short8*)(W0hi + (size_t)wrow * 128 + kc * 32 + q * 8);
    w0l[kc] = *(const short8*)(W0lo + (size_t)wrow * 128 + kc * 32 + q * 8);
    w1h[kc] = *(const short8*)(W1hi + (size_t)wrow * 128 + kc * 32 + q * 8);
    w1l[kc] = *(const short8*)(W1lo + (size_t)wrow * 128 + kc * 32 + q * 8);
    wsh[kc] = *(const short8*)(WShi + (size_t)wrow * 128 + kc * 32 + q * 8);
    wsl[kc] = *(const short8*)(WSlo + (size_t)wrow * 128 + kc * 32 + q * 8);
  }
  const float bias1 = b0e[b * 128 + wrow];
  const float bias2 = bse[b * 128 + wrow];

  for (int it = 0; it < 2; it++) {
    const int rowBase = blockIdx.x * 128 + it * 64;
    __syncthreads();  // prev oT store complete; At free
    {
      int r = tid >> 3, cs = (tid & 7) * 16;
      short8 v0 = *(const short8*)(hin + (size_t)(rowBase + r) * 128 + cs);
      short8 v1 = *(const short8*)(hin + (size_t)(rowBase + r) * 128 + cs + 8);
      *(short8*)(&At[r * 136 + cs]) = v0;
      *(short8*)(&At[r * 136 + cs + 8]) = v1;
    }
    __syncthreads();  // At ready
    // phase 1: net = relu(H) @ W0 + b0e
    f32x4 C1[4];
#pragma unroll
    for (int s = 0; s < 4; s++) C1[s] = (f32x4){bias1, bias1, bias1, bias1};
#pragma unroll
    for (int kc = 0; kc < 4; kc++) {
#pragma unroll
      for (int s = 0; s < 4; s++) {
        short8 Ar = relu8(*(const short8*)(&At[(s * 16 + l15) * 136 + kc * 32 + q * 8]));
        C1[s] = MFMA16(Ar, w0h[kc], C1[s]);
        C1[s] = MFMA16(Ar, w0l[kc], C1[s]);
      }
    }
#pragma unroll
    for (int s = 0; s < 4; s++)
#pragma unroll
      for (int r = 0; r < 4; r++)
        m2[(s * 16 + q * 4 + r) * 136 + nt * 16 + l15] =
            f32_to_bf16(fmaxf(C1[s][r], 0.f));
    __syncthreads();  // m2 ready
    // phase 2: h' = m2 @ W1 + H @ WS + bse
    f32x4 C2[4];
#pragma unroll
    for (int s = 0; s < 4; s++) C2[s] = (f32x4){bias2, bias2, bias2, bias2};
#pragma unroll
    for (int kc = 0; kc < 4; kc++) {
#pragma unroll
      for (int s = 0; s < 4; s++) {
        short8 Am = *(const short8*)(&m2[(s * 16 + l15) * 136 + kc * 32 + q * 8]);
        short8 Ah = *(const short8*)(&At[(s * 16 + l15) * 136 + kc * 32 + q * 8]);
        C2[s] = MFMA16(Am, w1h[kc], C2[s]);
        C2[s] = MFMA16(Am, w1l[kc], C2[s]);
        C2[s] = MFMA16(Ah, wsh[kc], C2[s]);
        C2[s] = MFMA16(Ah, wsl[kc], C2[s]);
      }
    }
#pragma unroll
    for (int s = 0; s < 4; s++)
#pragma unroll
      for (int r = 0; r < 4; r++)
        oT[(s * 16 + q * 4 + r) * 136 + nt * 16 + l15] = f32_to_bf16(C2[s][r]);
    if (doPool) {
      float m = -1e30f;
#pragma unroll
      for (int s = 0; s < 4; s++)
#pragma unroll
        for (int r = 0; r < 4; r++) m = fmaxf(m, C2[s][r]);
      m = fmaxf(m, __shfl_xor(m, 16, 64));
      m = fmaxf(m, __shfl_xor(m, 32, 64));
      if (lane < 16) atomicMax(&pool[b * 128 + nt * 16 + lane], f32_key(m));
    }
    __syncthreads();  // oT ready; m2/At reads done
    {
      int r = tid >> 3, cs = (tid & 7) * 16;
      short8 v0 = *(const short8*)(&oT[r * 136 + cs]);
      short8 v1 = *(const short8*)(&oT[r * 136 + cs + 8]);
      *(short8*)(hout + (size_t)(rowBase + r) * 128 + cs) = v0;
      *(short8*)(hout + (size_t)(rowBase + r) * 128 + cs + 8) = v1;
    }
  }
}

// ---------------- fold: per-batch effective biases from pool ---------------
__global__ void fold_kernel(const unsigned int* __restrict__ pool,
                            const float* __restrict__ b0s,
                            const float* __restrict__ b1s,
                            const float* __restrict__ w0hi,  // f32, rows 128..255
                            const float* __restrict__ wshi,
                            float* __restrict__ b0e, float* __restrict__ bse) {
  __shared__ float ps[256];
  int tid = threadIdx.x;  // 256
  int b = tid >> 7, j = tid & 127;
  ps[tid] = key_f32(pool[tid]);
  __syncthreads();
  float a0 = b0s[j], a1 = b1s[j];
  for (int ch = 0; ch < 128; ch++) {
    float pv = ps[b * 128 + ch];
    a0 = fmaf(fmaxf(pv, 0.f), w0hi[ch * HD + j], a0);
    a1 = fmaf(pv, wshi[ch * HD + j], a1);
  }
  b0e[b * 128 + j] = a0;
  bse[b * 128 + j] = a1;
}

extern "C" void kernel_launch(void* const* d_in, const int* in_sizes, int n_in,
                              void* d_out, int out_size, void* d_ws,
                              size_t ws_size, hipStream_t stream) {
  const float* p   = (const float*)d_in[0];
  const float* fcw = (const float*)d_in[1];
  const float* fcb = (const float*)d_in[2];
  const float* w0  = (const float*)d_in[3];
  const float* b0  = (const float*)d_in[4];
  const float* w1  = (const float*)d_in[5];
  const float* b1  = (const float*)d_in[6];
  const float* wsc = (const float*)d_in[7];
  float* out = (float*)d_out;

  char* wsp = (char*)d_ws;
  unsigned short* hA = (unsigned short*)wsp;
  unsigned short* hB = hA + (size_t)G_ALL * HD;
  unsigned short* B0hi = hB + (size_t)G_ALL * HD;
  unsigned short* B0lo = B0hi + 32768;
  unsigned short* W0hi = B0lo + 32768;   // [4][128][128]
  unsigned short* W0lo = W0hi + 65536;
  unsigned short* W1hi = W0lo + 65536;   // [5][128][128]
  unsigned short* W1lo = W1hi + 81920;
  unsigned short* WShi = W1lo + 81920;   // [4][128][128]
  unsigned short* WSlo = WShi + 65536;
  unsigned int* pool = (unsigned int*)(WSlo + 65536);  // [4][2][128]
  float* b0e = (float*)(pool + 1024);    // [4][2][128]
  float* bse = b0e + 1024;
  float* Sp  = bse + 1024;               // [3][128]
  float* bsp = Sp + 384;                 // [128]
  int* hist    = (int*)(bsp + 128);      // [2][16384] (becomes cursor)
  int* offsets = hist + 2 * NBINS;       // [2*16384 + 1] (+pad)
  int* order   = offsets + 2 * NBINS + 4;  // [131072]

  prep_kernel<<<1, 128, 0, stream>>>(fcw, fcb, wsc, Sp, bsp, pool, hist);
  wprep_kernel<<<960, 256, 0, stream>>>(w0, w1, wsc, B0hi, B0lo, W0hi, W0lo,
                                        W1hi, W1lo, WShi, WSlo);
  index_kernel<<<512, 256, 0, stream>>>(p, hist);
  scan_kernel<<<1, 1024, 0, stream>>>(hist, offsets);
  fill_kernel<<<512, 256, 0, stream>>>(p, hist, order);

  stage0_kernel<<<1024, 512, 0, stream>>>(p, fcw, fcb, B0hi, B0lo, W1hi, W1lo,
                                          b0, b1, Sp, bsp, hA, pool);
  unsigned short* hin = hA;
  unsigned short* hout = hB;
  for (int s = 1; s < 5; s++) {
    fold_kernel<<<1, 256, 0, stream>>>(
        pool + (s - 1) * 256, b0 + s * HD, b1 + s * HD,
        w0 + (size_t)(s * 256 + 128) * HD, wsc + (size_t)(s * 256 + 128) * HD,
        b0e + (s - 1) * 256, bse + (s - 1) * 256);
    stageN_kernel<<<1024, 512, 0, stream>>>(
        hin, hout, W0hi + (s - 1) * 16384, W0lo + (s - 1) * 16384,
        W1hi + s * 16384, W1lo + s * 16384, WShi + (s - 1) * 16384,
        WSlo + (s - 1) * 16384, b0e + (s - 1) * 256, bse + (s - 1) * 256,
        pool + s * 256, (s < 4) ? 1 : 0);
    unsigned short* t = hin; hin = hout; hout = t;
  }
  gather_kernel<<<512, 256, 0, stream>>>(hin, offsets, order, out);
}

// Round 5
// 473.205 us; speedup vs baseline: 28.1863x; 1.1311x over previous
//
#include <hip/hip_runtime.h>
#include <hip/hip_bf16.h>

// LocalResnetPointnet v5: weight-stationary MFMA stages, 512 blocks x 4 tiles
// (weight-load amortization), stride-8 fc_pos channels (bank-conflict fix),
// sort-based scatter-mean.

#define G_ALL 131072   // B*T
#define HD    128
#define NBINS 16384

typedef __attribute__((ext_vector_type(8))) short short8;
typedef __attribute__((ext_vector_type(4))) float f32x4;

#define MFMA16(a, b, c) __builtin_amdgcn_mfma_f32_16x16x32_bf16(a, b, c, 0, 0, 0)

__device__ __forceinline__ float bf16_to_f32(unsigned short u) {
  union { unsigned int u; float f; } v; v.u = ((unsigned int)u) << 16; return v.f;
}
__device__ __forceinline__ unsigned short f32_to_bf16(float f) {
  union { float f; unsigned int u; } v; v.f = f;
  unsigned int u = v.u;
  u += 0x7fffu + ((u >> 16) & 1u);   // RNE (no NaNs in this workload)
  return (unsigned short)(u >> 16);
}
// order-preserving float -> uint key for atomicMax
__device__ __forceinline__ unsigned int f32_key(float f) {
  union { float f; unsigned int u; } v; v.f = f;
  return (v.u & 0x80000000u) ? ~v.u : (v.u | 0x80000000u);
}
__device__ __forceinline__ float key_f32(unsigned int k) {
  union { unsigned int u; float f; } v;
  v.u = (k & 0x80000000u) ? (k & 0x7fffffffu) : ~k;
  return v.f;
}
__device__ __forceinline__ int bin_of(float p0, float p2) {
  float x = p0 / 1.101f + 0.5f;
  x = fminf(fmaxf(x, 0.0f), 1.0f - 1e-6f);
  int xi = (int)(x * 128.0f);
  float z = p2 / 1.101f + 0.5f;
  z = fminf(fmaxf(z, 0.0f), 1.0f - 1e-6f);
  int zi = (int)(z * 128.0f);
  return xi + 128 * zi;
}
__device__ __forceinline__ short8 relu8(short8 a) {
  short8 r;
#pragma unroll
  for (int e = 0; e < 8; e++) r[e] = a[e] < 0 ? (short)0 : a[e];
  return r;
}

// ---------------- prep: Sp = fcw@ws0, bsp = fcb@ws0, zero pools+hist -------
__global__ void prep_kernel(const float* __restrict__ fcw,
                            const float* __restrict__ fcb,
                            const float* __restrict__ ws0,
                            float* __restrict__ Sp, float* __restrict__ bsp,
                            unsigned int* __restrict__ pool,
                            int* __restrict__ hist) {
  int j = threadIdx.x;  // 128 threads
  for (int d = 0; d < 3; d++) {
    float s = 0.f;
    for (int ch = 0; ch < 256; ch++)
      s = fmaf(fcw[d * 256 + ch], ws0[ch * HD + j], s);
    Sp[d * HD + j] = s;
  }
  float s = 0.f;
  for (int ch = 0; ch < 256; ch++)
    s = fmaf(fcb[ch], ws0[ch * HD + j], s);
  bsp[j] = s;
  for (int k = j; k < 4 * 2 * 128; k += 128) pool[k] = 0u;
  for (int k = j; k < 2 * NBINS; k += 128) hist[k] = 0;
}

// ---------------- weight transform: transpose + bf16 hi/lo split -----------
__global__ void wprep_kernel(const float* __restrict__ w0,
                             const float* __restrict__ w1,
                             const float* __restrict__ ws,
                             unsigned short* __restrict__ B0hi, unsigned short* __restrict__ B0lo,
                             unsigned short* __restrict__ W0hi, unsigned short* __restrict__ W0lo,
                             unsigned short* __restrict__ W1hi, unsigned short* __restrict__ W1lo,
                             unsigned short* __restrict__ WShi, unsigned short* __restrict__ WSlo) {
  int gid = blockIdx.x * 256 + threadIdx.x;
  float v;
  unsigned short *hi, *lo;
  int dst;
  if (gid < 32768) {                       // B0t: [n][k] from w0[0] (256x128)
    int n = gid >> 8, k = gid & 255;
    v = w0[k * 128 + n];
    hi = B0hi; lo = B0lo; dst = gid;
  } else if (gid < 98304) {                // W0t stages 1..4, rows 0..127
    int i = gid - 32768; int s = i >> 14; int n = (i >> 7) & 127; int k = i & 127;
    v = w0[(size_t)((s + 1) * 256 + k) * 128 + n];
    hi = W0hi; lo = W0lo; dst = i;
  } else if (gid < 180224) {               // W1t stages 0..4
    int i = gid - 98304; int s = i >> 14; int n = (i >> 7) & 127; int k = i & 127;
    v = w1[(size_t)(s * 128 + k) * 128 + n];
    hi = W1hi; lo = W1lo; dst = i;
  } else if (gid < 245760) {               // WSt stages 1..4, rows 0..127
    int i = gid - 180224; int s = i >> 14; int n = (i >> 7) & 127; int k = i & 127;
    v = ws[(size_t)((s + 1) * 256 + k) * 128 + n];
    hi = WShi; lo = WSlo; dst = i;
  } else return;
  unsigned short h = f32_to_bf16(v);
  hi[dst] = h;
  lo[dst] = f32_to_bf16(v - bf16_to_f32(h));
}

// ---------------- scatter pipeline -----------------------------------------
__global__ __launch_bounds__(256) void index_kernel(const float* __restrict__ p,
                                                    int* __restrict__ hist) {
  int g = blockIdx.x * 256 + threadIdx.x;
  int b = g >> 16;
  int idx = bin_of(p[3 * (size_t)g], p[3 * (size_t)g + 2]);
  atomicAdd(&hist[b * NBINS + idx], 1);
}

__global__ __launch_bounds__(1024) void scan_kernel(int* __restrict__ hist,
                                                    int* __restrict__ offsets) {
  __shared__ int sd[1024];
  int t = threadIdx.x;
  int vals[32];
  int s = 0;
#pragma unroll
  for (int i = 0; i < 32; i++) { vals[i] = hist[t * 32 + i]; s += vals[i]; }
  sd[t] = s;
  __syncthreads();
  for (int d = 1; d < 1024; d <<= 1) {
    int v = (t >= d) ? sd[t - d] : 0;
    __syncthreads();
    sd[t] += v;
    __syncthreads();
  }
  int run = sd[t] - s;  // exclusive prefix
#pragma unroll
  for (int i = 0; i < 32; i++) {
    offsets[t * 32 + i] = run;
    hist[t * 32 + i] = run;  // cursor copy (in-place)
    run += vals[i];
  }
  if (t == 1023) offsets[32768] = run;  // sentinel = G_ALL
}

__global__ __launch_bounds__(256) void fill_kernel(const float* __restrict__ p,
                                                   int* __restrict__ cursor,
                                                   int* __restrict__ order) {
  int g = blockIdx.x * 256 + threadIdx.x;
  int b = g >> 16;
  int idx = bin_of(p[3 * (size_t)g], p[3 * (size_t)g + 2]);
  int pos = atomicAdd(&cursor[b * NBINS + idx], 1);
  order[pos] = g;
}

// gather + mean: one wave per 16 bins; writes EVERY output element.
__global__ __launch_bounds__(256) void gather_kernel(
    const unsigned short* __restrict__ c, const int* __restrict__ offsets,
    const int* __restrict__ order, float* __restrict__ out) {
  int wave = threadIdx.x >> 6, lane = threadIdx.x & 63;
  int b = blockIdx.x >> 8;
  int binBase = (blockIdx.x & 255) * 64 + wave * 16;
  for (int bi = 0; bi < 16; bi++) {
    int B = b * NBINS + binBase + bi;
    int st = offsets[B], en = offsets[B + 1];
    float a0 = 0.f, a1 = 0.f;
    for (int k = st; k < en; k++) {
      int g = order[k];
      unsigned int u = *(const unsigned int*)(c + (size_t)g * HD + lane * 2);
      a0 += bf16_to_f32((unsigned short)(u & 0xffffu));
      a1 += bf16_to_f32((unsigned short)(u >> 16));
    }
    float cf = fmaxf((float)(en - st), 1.0f);
    size_t base = (size_t)b * HD * NBINS + (size_t)(binBase + bi);
    out[base + (size_t)(2 * lane) * NBINS] = a0 / cf;
    out[base + (size_t)(2 * lane + 1) * NBINS] = a1 / cf;
  }
}

// ---------------- stage 0: fc_pos + block0 (weight-stationary MFMA) --------
// 8 waves; wave = nt (16 output ch). 512 blocks x 4 tiles of 64 rows.
__global__ __launch_bounds__(512, 4) void stage0_kernel(
    const float* __restrict__ p, const float* __restrict__ fcw,
    const float* __restrict__ fcb,
    const unsigned short* __restrict__ B0hi, const unsigned short* __restrict__ B0lo,
    const unsigned short* __restrict__ W1hi, const unsigned short* __restrict__ W1lo,
    const float* __restrict__ b0, const float* __restrict__ b1,
    const float* __restrict__ Sp, const float* __restrict__ bsp,
    unsigned short* __restrict__ hout, unsigned int* __restrict__ pool) {
  __shared__ float fcL[1024];                // fcw (768) + fcb (256)
  __shared__ float ptL[64 * 4];
  __shared__ unsigned short x0t[64 * 264];   // K=256 relu tile; rows 0..32 reused as out tile
  __shared__ unsigned short m2[64 * 136];
  const int tid = threadIdx.x;
  const int lane = tid & 63;
  const int q = lane >> 4, l15 = lane & 15;
  const int nt = tid >> 6;                   // wave id = output-ch tile
  const int b = blockIdx.x >> 8;
  const int wrow = nt * 16 + l15;

  // weights -> registers (once per kernel)
  short8 b0h[8], b0l[8], w1h[4], w1l[4];
#pragma unroll
  for (int kc = 0; kc < 8; kc++) {
    b0h[kc] = *(const short8*)(B0hi + (size_t)wrow * 256 + kc * 32 + q * 8);
    b0l[kc] = *(const short8*)(B0lo + (size_t)wrow * 256 + kc * 32 + q * 8);
  }
#pragma unroll
  for (int kc = 0; kc < 4; kc++) {
    w1h[kc] = *(const short8*)(W1hi + (size_t)wrow * 128 + kc * 32 + q * 8);
    w1l[kc] = *(const short8*)(W1lo + (size_t)wrow * 128 + kc * 32 + q * 8);
  }
  const float bias1 = b0[wrow];
  const float bias2 = bsp[wrow] + b1[wrow];
  const float sp0 = Sp[wrow], sp1 = Sp[128 + wrow], sp2 = Sp[256 + wrow];

  for (int k = tid; k < 1024; k += 512)
    fcL[k] = (k < 768) ? fcw[k] : fcb[k - 768];

  for (int it = 0; it < 4; it++) {
    const int rowBase = (blockIdx.x * 4 + it) * 64;
    __syncthreads();  // fcL ready (it0) / prev out-store complete
    if (tid < 192) ptL[(tid / 3) * 4 + (tid % 3)] = p[(size_t)rowBase * 3 + tid];
    // fc_pos: row = tid>>3; channels strided by 8 (bank-conflict-free fcL reads)
    {
      int row = tid >> 3, c8 = tid & 7;
      const float* pr = p + (size_t)(rowBase + row) * 3;
      float p0 = pr[0], p1 = pr[1], p2 = pr[2];
#pragma unroll
      for (int cc = 0; cc < 32; cc++) {
        int ch = c8 + cc * 8;
        float x = fcL[768 + ch] + p0 * fcL[ch] + p1 * fcL[256 + ch] + p2 * fcL[512 + ch];
        x0t[row * 264 + ch] = f32_to_bf16(fmaxf(x, 0.f));
      }
    }
    __syncthreads();  // x0t + ptL ready
    // phase 1: net = relu(x0) @ W0[0] + b0[0]  (K=256)
    f32x4 C1[4];
#pragma unroll
    for (int s = 0; s < 4; s++) C1[s] = (f32x4){bias1, bias1, bias1, bias1};
#pragma unroll
    for (int kc = 0; kc < 8; kc++) {
#pragma unroll
      for (int s = 0; s < 4; s++) {
        short8 Ar = *(const short8*)(&x0t[(s * 16 + l15) * 264 + kc * 32 + q * 8]);
        C1[s] = MFMA16(Ar, b0h[kc], C1[s]);
        C1[s] = MFMA16(Ar, b0l[kc], C1[s]);
      }
    }
#pragma unroll
    for (int s = 0; s < 4; s++)
#pragma unroll
      for (int r = 0; r < 4; r++)
        m2[(s * 16 + q * 4 + r) * 136 + nt * 16 + l15] =
            f32_to_bf16(fmaxf(C1[s][r], 0.f));
    __syncthreads();  // m2 ready; x0t phase-1 reads done -> reuse as out tile
    // phase 2: h = m2 @ W1[0] + (p @ Sp + bsp + b1[0])
    f32x4 C2[4];
#pragma unroll
    for (int s = 0; s < 4; s++)
#pragma unroll
      for (int r = 0; r < 4; r++) {
        int row = s * 16 + q * 4 + r;
        C2[s][r] = bias2 + ptL[row * 4] * sp0 + ptL[row * 4 + 1] * sp1 +
                   ptL[row * 4 + 2] * sp2;
      }
#pragma unroll
    for (int kc = 0; kc < 4; kc++) {
#pragma unroll
      for (int s = 0; s < 4; s++) {
        short8 Am = *(const short8*)(&m2[(s * 16 + l15) * 136 + kc * 32 + q * 8]);
        C2[s] = MFMA16(Am, w1h[kc], C2[s]);
        C2[s] = MFMA16(Am, w1l[kc], C2[s]);
      }
    }
#pragma unroll
    for (int s = 0; s < 4; s++)
#pragma unroll
      for (int r = 0; r < 4; r++)
        x0t[(s * 16 + q * 4 + r) * 136 + nt * 16 + l15] = f32_to_bf16(C2[s][r]);
    {
      float m = -1e30f;
#pragma unroll
      for (int s = 0; s < 4; s++)
#pragma unroll
        for (int r = 0; r < 4; r++) m = fmaxf(m, C2[s][r]);
      m = fmaxf(m, __shfl_xor(m, 16, 64));
      m = fmaxf(m, __shfl_xor(m, 32, 64));
      if (lane < 16) atomicMax(&pool[b * 128 + nt * 16 + lane], f32_key(m));
    }
    __syncthreads();  // out tile ready
    {
      int r = tid >> 3, cs = (tid & 7) * 16;
      short8 v0 = *(const short8*)(&x0t[r * 136 + cs]);
      short8 v1 = *(const short8*)(&x0t[r * 136 + cs + 8]);
      *(short8*)(hout + (size_t)(rowBase + r) * 128 + cs) = v0;
      *(short8*)(hout + (size_t)(rowBase + r) * 128 + cs + 8) = v1;
    }
  }
}

// ---------------- stages 1..4 (weight-stationary MFMA) ---------------------
// 8 waves; wave = nt. 512 blocks x 4 tiles of 64 rows. oT reuses At region.
__global__ __launch_bounds__(512, 4) void stageN_kernel(
    const unsigned short* __restrict__ hin, unsigned short* __restrict__ hout,
    const unsigned short* __restrict__ W0hi, const unsigned short* __restrict__ W0lo,
    const unsigned short* __restrict__ W1hi, const unsigned short* __restrict__ W1lo,
    const unsigned short* __restrict__ WShi, const unsigned short* __restrict__ WSlo,
    const float* __restrict__ b0e, const float* __restrict__ bse,
    unsigned int* __restrict__ pool, int doPool) {
  __shared__ unsigned short At[64 * 136];   // H tile; reused as output tile
  __shared__ unsigned short m2[64 * 136];   // relu(net) tile
  const int tid = threadIdx.x;
  const int lane = tid & 63;
  const int q = lane >> 4, l15 = lane & 15;
  const int nt = tid >> 6;
  const int b = blockIdx.x >> 8;
  const int wrow = nt * 16 + l15;

  short8 w0h[4], w0l[4], w1h[4], w1l[4], wsh[4], wsl[4];
#pragma unroll
  for (int kc = 0; kc < 4; kc++) {
    w0h[kc] = *(const short8*)(W0hi + (size_t)wrow * 128 + kc * 32 + q * 8);
    w0l[kc] = *(const short8*)(W0lo + (size_t)wrow * 128 + kc * 32 + q * 8);
    w1h[kc] = *(const short8*)(W1hi + (size_t)wrow * 128 + kc * 32 + q * 8);
    w1l[kc] = *(const short8*)(W1lo + (size_t)wrow * 128 + kc * 32 + q * 8);
    wsh[kc] = *(const short8*)(WShi + (size_t)wrow * 128 + kc * 32 + q * 8);
    wsl[kc] = *(const short8*)(WSlo + (size_t)wrow * 128 + kc * 32 + q * 8);
  }
  const float bias1 = b0e[b * 128 + wrow];
  const float bias2 = bse[b * 128 + wrow];

  for (int it = 0; it < 4; it++) {
    const int rowBase = (blockIdx.x * 4 + it) * 64;
    __syncthreads();  // prev store complete; At writable
    {
      int r = tid >> 3, cs = (tid & 7) * 16;
      short8 v0 = *(const short8*)(hin + (size_t)(rowBase + r) * 128 + cs);
      short8 v1 = *(const short8*)(hin + (size_t)(rowBase + r) * 128 + cs + 8);
      *(short8*)(&At[r * 136 + cs]) = v0;
      *(short8*)(&At[r * 136 + cs + 8]) = v1;
    }
    __syncthreads();  // At ready
    // phase 1: net = relu(H) @ W0 + b0e  (+ H @ WS shortcut deferred)
    f32x4 C1[4];
#pragma unroll
    for (int s = 0; s < 4; s++) C1[s] = (f32x4){bias1, bias1, bias1, bias1};
#pragma unroll
    for (int kc = 0; kc < 4; kc++) {
#pragma unroll
      for (int s = 0; s < 4; s++) {
        short8 Ar = relu8(*(const short8*)(&At[(s * 16 + l15) * 136 + kc * 32 + q * 8]));
        C1[s] = MFMA16(Ar, w0h[kc], C1[s]);
        C1[s] = MFMA16(Ar, w0l[kc], C1[s]);
      }
    }
#pragma unroll
    for (int s = 0; s < 4; s++)
#pragma unroll
      for (int r = 0; r < 4; r++)
        m2[(s * 16 + q * 4 + r) * 136 + nt * 16 + l15] =
            f32_to_bf16(fmaxf(C1[s][r], 0.f));
    __syncthreads();  // m2 ready
    // phase 2: h' = m2 @ W1 + H @ WS + bse
    f32x4 C2[4];
#pragma unroll
    for (int s = 0; s < 4; s++) C2[s] = (f32x4){bias2, bias2, bias2, bias2};
#pragma unroll
    for (int kc = 0; kc < 4; kc++) {
#pragma unroll
      for (int s = 0; s < 4; s++) {
        short8 Am = *(const short8*)(&m2[(s * 16 + l15) * 136 + kc * 32 + q * 8]);
        short8 Ah = *(const short8*)(&At[(s * 16 + l15) * 136 + kc * 32 + q * 8]);
        C2[s] = MFMA16(Am, w1h[kc], C2[s]);
        C2[s] = MFMA16(Am, w1l[kc], C2[s]);
        C2[s] = MFMA16(Ah, wsh[kc], C2[s]);
        C2[s] = MFMA16(Ah, wsl[kc], C2[s]);
      }
    }
    __syncthreads();  // all At/m2 reads done -> At reusable as out tile
#pragma unroll
    for (int s = 0; s < 4; s++)
#pragma unroll
      for (int r = 0; r < 4; r++)
        At[(s * 16 + q * 4 + r) * 136 + nt * 16 + l15] = f32_to_bf16(C2[s][r]);
    if (doPool) {
      float m = -1e30f;
#pragma unroll
      for (int s = 0; s < 4; s++)
#pragma unroll
        for (int r = 0; r < 4; r++) m = fmaxf(m, C2[s][r]);
      m = fmaxf(m, __shfl_xor(m, 16, 64));
      m = fmaxf(m, __shfl_xor(m, 32, 64));
      if (lane < 16) atomicMax(&pool[b * 128 + nt * 16 + lane], f32_key(m));
    }
    __syncthreads();  // out tile ready
    {
      int r = tid >> 3, cs = (tid & 7) * 16;
      short8 v0 = *(const short8*)(&At[r * 136 + cs]);
      short8 v1 = *(const short8*)(&At[r * 136 + cs + 8]);
      *(short8*)(hout + (size_t)(rowBase + r) * 128 + cs) = v0;
      *(short8*)(hout + (size_t)(rowBase + r) * 128 + cs + 8) = v1;
    }
  }
}

// ---------------- fold: per-batch effective biases from pool ---------------
__global__ void fold_kernel(const unsigned int* __restrict__ pool,
                            const float* __restrict__ b0s,
                            const float* __restrict__ b1s,
                            const float* __restrict__ w0hi,  // f32, rows 128..255
                            const float* __restrict__ wshi,
                            float* __restrict__ b0e, float* __restrict__ bse) {
  __shared__ float ps[256];
  int tid = threadIdx.x;  // 256
  int b = tid >> 7, j = tid & 127;
  ps[tid] = key_f32(pool[tid]);
  __syncthreads();
  float a0 = b0s[j], a1 = b1s[j];
  for (int ch = 0; ch < 128; ch++) {
    float pv = ps[b * 128 + ch];
    a0 = fmaf(fmaxf(pv, 0.f), w0hi[ch * HD + j], a0);
    a1 = fmaf(pv, wshi[ch * HD + j], a1);
  }
  b0e[b * 128 + j] = a0;
  bse[b * 128 + j] = a1;
}

extern "C" void kernel_launch(void* const* d_in, const int* in_sizes, int n_in,
                              void* d_out, int out_size, void* d_ws,
                              size_t ws_size, hipStream_t stream) {
  const float* p   = (const float*)d_in[0];
  const float* fcw = (const float*)d_in[1];
  const float* fcb = (const float*)d_in[2];
  const float* w0  = (const float*)d_in[3];
  const float* b0  = (const float*)d_in[4];
  const float* w1  = (const float*)d_in[5];
  const float* b1  = (const float*)d_in[6];
  const float* wsc = (const float*)d_in[7];
  float* out = (float*)d_out;

  char* wsp = (char*)d_ws;
  unsigned short* hA = (unsigned short*)wsp;
  unsigned short* hB = hA + (size_t)G_ALL * HD;
  unsigned short* B0hi = hB + (size_t)G_ALL * HD;
  unsigned short* B0lo = B0hi + 32768;
  unsigned short* W0hi = B0lo + 32768;   // [4][128][128]
  unsigned short* W0lo = W0hi + 65536;
  unsigned short* W1hi = W0lo + 65536;   // [5][128][128]
  unsigned short* W1lo = W1hi + 81920;
  unsigned short* WShi = W1lo + 81920;   // [4][128][128]
  unsigned short* WSlo = WShi + 65536;
  unsigned int* pool = (unsigned int*)(WSlo + 65536);  // [4][2][128]
  float* b0e = (float*)(pool + 1024);    // [4][2][128]
  float* bse = b0e + 1024;
  float* Sp  = bse + 1024;               // [3][128]
  float* bsp = Sp + 384;                 // [128]
  int* hist    = (int*)(bsp + 128);      // [2][16384] (becomes cursor)
  int* offsets = hist + 2 * NBINS;       // [2*16384 + 1] (+pad)
  int* order   = offsets + 2 * NBINS + 4;  // [131072]

  prep_kernel<<<1, 128, 0, stream>>>(fcw, fcb, wsc, Sp, bsp, pool, hist);
  wprep_kernel<<<960, 256, 0, stream>>>(w0, w1, wsc, B0hi, B0lo, W0hi, W0lo,
                                        W1hi, W1lo, WShi, WSlo);
  index_kernel<<<512, 256, 0, stream>>>(p, hist);
  scan_kernel<<<1, 1024, 0, stream>>>(hist, offsets);
  fill_kernel<<<512, 256, 0, stream>>>(p, hist, order);

  stage0_kernel<<<512, 512, 0, stream>>>(p, fcw, fcb, B0hi, B0lo, W1hi, W1lo,
                                         b0, b1, Sp, bsp, hA, pool);
  unsigned short* hin = hA;
  unsigned short* hout = hB;
  for (int s = 1; s < 5; s++) {
    fold_kernel<<<1, 256, 0, stream>>>(
        pool + (s - 1) * 256, b0 + s * HD, b1 + s * HD,
        w0 + (size_t)(s * 256 + 128) * HD, wsc + (size_t)(s * 256 + 128) * HD,
        b0e + (s - 1) * 256, bse + (s - 1) * 256);
    stageN_kernel<<<512, 512, 0, stream>>>(
        hin, hout, W0hi + (s - 1) * 16384, W0lo + (s - 1) * 16384,
        W1hi + s * 16384, W1lo + s * 16384, WShi + (s - 1) * 16384,
        WSlo + (s - 1) * 16384, b0e + (s - 1) * 256, bse + (s - 1) * 256,
        pool + s * 256, (s < 4) ? 1 : 0);
    unsigned short* t = hin; hin = hout; hout = t;
  }
  gather_kernel<<<512, 256, 0, stream>>>(hin, offsets, order, out);
}